// Round 1
// baseline (736.131 us; speedup 1.0000x reference)
//
#include <hip/hip_runtime.h>
#include <hip/hip_bf16.h>

// ED_Fourth_MOE: conv3d x2 -> 5x MoE(top-1 of 4 experts, D=1024,HID=2048) -> poly+sigmoid
// Round 1: first complete implementation. Correctness-first, moderate optimization.
//
// Pipeline:
//   conv_tok:    fused conv1(3x3x3,pad1,relu)+conv2(10x10x3x3,relu) per batch -> tok (f32+bf16)
//   gating:      fp32 logits, argmax expert per (module, token), atomic counts
//   scatter:     compact token lists per (module, expert)
//   per module:  transpose w1 -> bf16 N-major | grouped GEMM1 (relu, bf16 h)
//                transpose w2 -> bf16 N-major | grouped GEMM2 (f32, scatter to moe_out)
//   poly:        sigmoid(i4*f4 + i3*f3 + i2*f2 + i*f1 + f0), broadcast over T
//   loss:        2e-2 * var(counts,ddof=1)/256^2 summed over modules
//
// Workspace: 48.3 MB total.

typedef __bf16 bf16x8 __attribute__((ext_vector_type(8)));
typedef __bf16 bf16x4 __attribute__((ext_vector_type(4)));
typedef float f32x4 __attribute__((ext_vector_type(4)));

#define NMOE 5
#define NEXP 4
#define BDIM 1024
#define DDIM 1024
#define HIDDIM 2048

// ---------------------------------------------------------------- conv fused
// One block per batch image. 256 threads: col = tid&31, rows 4*(tid>>5)..+3.
// LDS: padded input [10][34][34] + padded conv1 plane [34][34].
__global__ __launch_bounds__(256) void conv_tok_kernel(
    const float* __restrict__ input, const float* __restrict__ c1w,
    const float* __restrict__ c1b, const float* __restrict__ c2w,
    const float* __restrict__ c2b, float* __restrict__ tok_f32,
    __bf16* __restrict__ tok_bf16)
{
    __shared__ float in_s[10][34][34];
    __shared__ float P[34][34];
    const int b = blockIdx.x, tid = threadIdx.x;

    float* ls = &in_s[0][0][0];
    for (int i = tid; i < 10 * 34 * 34; i += 256) ls[i] = 0.f;
    for (int i = tid; i < 34 * 34; i += 256) (&P[0][0])[i] = 0.f;
    __syncthreads();

    const float* ip = input + (size_t)b * 10240;
    for (int i = tid; i < 2560; i += 256) {
        int t = i >> 8, rem = i & 255;
        int h = rem >> 3, w4 = rem & 7;
        float4 v = ((const float4*)ip)[i];
        float* dst = &in_s[t][h + 1][w4 * 4 + 1];
        dst[0] = v.x; dst[1] = v.y; dst[2] = v.z; dst[3] = v.w;
    }
    __syncthreads();

    const int wcol = tid & 31;
    const int r0 = (tid >> 5) * 4;
    const float c2bias = c2b[0];
    float tk0 = c2bias, tk1 = c2bias, tk2 = c2bias, tk3 = c2bias;

    for (int c = 0; c < 10; ++c) {
        float w1l[27];
        #pragma unroll
        for (int i = 0; i < 27; ++i) w1l[i] = c1w[c * 27 + i];
        const float c1bias = c1b[c];
        for (int t = 0; t < 10; ++t) {
            float a0 = c1bias, a1 = c1bias, a2 = c1bias, a3 = c1bias;
            #pragma unroll
            for (int dt = 0; dt < 3; ++dt) {
                int ts = t + dt - 1;
                if (ts < 0 || ts >= 10) continue;
                #pragma unroll
                for (int dw = 0; dw < 3; ++dw) {
                    float v0 = in_s[ts][r0 + 0][wcol + dw];
                    float v1 = in_s[ts][r0 + 1][wcol + dw];
                    float v2 = in_s[ts][r0 + 2][wcol + dw];
                    float v3 = in_s[ts][r0 + 3][wcol + dw];
                    float v4 = in_s[ts][r0 + 4][wcol + dw];
                    float v5 = in_s[ts][r0 + 5][wcol + dw];
                    float u0 = w1l[dt * 9 + 0 + dw];
                    float u1 = w1l[dt * 9 + 3 + dw];
                    float u2 = w1l[dt * 9 + 6 + dw];
                    a0 += u0 * v0 + u1 * v1 + u2 * v2;
                    a1 += u0 * v1 + u1 * v2 + u2 * v3;
                    a2 += u0 * v2 + u1 * v3 + u2 * v4;
                    a3 += u0 * v3 + u1 * v4 + u2 * v5;
                }
            }
            __syncthreads();   // previous plane's conv2 reads done
            P[r0 + 1][wcol + 1] = fmaxf(a0, 0.f);
            P[r0 + 2][wcol + 1] = fmaxf(a1, 0.f);
            P[r0 + 3][wcol + 1] = fmaxf(a2, 0.f);
            P[r0 + 4][wcol + 1] = fmaxf(a3, 0.f);
            __syncthreads();
            const int wb = (c * 10 + t) * 9;
            #pragma unroll
            for (int dw = 0; dw < 3; ++dw) {
                float q0 = P[r0 + 0][wcol + dw];
                float q1 = P[r0 + 1][wcol + dw];
                float q2 = P[r0 + 2][wcol + dw];
                float q3 = P[r0 + 3][wcol + dw];
                float q4 = P[r0 + 4][wcol + dw];
                float q5 = P[r0 + 5][wcol + dw];
                float u0 = c2w[wb + 0 + dw];
                float u1 = c2w[wb + 3 + dw];
                float u2 = c2w[wb + 6 + dw];
                tk0 += u0 * q0 + u1 * q1 + u2 * q2;
                tk1 += u0 * q1 + u1 * q2 + u2 * q3;
                tk2 += u0 * q2 + u1 * q3 + u2 * q4;
                tk3 += u0 * q3 + u1 * q4 + u2 * q5;
            }
        }
    }
    float o0 = fmaxf(tk0, 0.f), o1 = fmaxf(tk1, 0.f);
    float o2 = fmaxf(tk2, 0.f), o3 = fmaxf(tk3, 0.f);
    size_t base = (size_t)b * 1024 + (size_t)r0 * 32 + wcol;
    tok_f32[base] = o0; tok_f32[base + 32] = o1;
    tok_f32[base + 64] = o2; tok_f32[base + 96] = o3;
    tok_bf16[base] = (__bf16)o0; tok_bf16[base + 32] = (__bf16)o1;
    tok_bf16[base + 64] = (__bf16)o2; tok_bf16[base + 96] = (__bf16)o3;
}

// ---------------------------------------------------------------- gating
// One wave per (module, token). fp32 dot (argmax must match fp32 reference).
__global__ __launch_bounds__(256) void gating_kernel(
    const float* __restrict__ tok, const float* __restrict__ w_gate,
    int* __restrict__ expert_id, int* __restrict__ counts)
{
    int gw = blockIdx.x * 4 + (threadIdx.x >> 6);
    int l = threadIdx.x & 63;
    int n = gw >> 10, b = gw & 1023;
    const float* trow = tok + (size_t)b * 1024;
    const float* wg = w_gate + (size_t)n * 4096;
    float a0 = 0.f, a1 = 0.f, a2 = 0.f, a3 = 0.f;
    #pragma unroll
    for (int i = 0; i < 16; ++i) {
        int d = i * 64 + l;
        float tv = trow[d];
        float4 g4 = *(const float4*)(wg + d * 4);
        a0 += tv * g4.x; a1 += tv * g4.y; a2 += tv * g4.z; a3 += tv * g4.w;
    }
    #pragma unroll
    for (int off = 32; off >= 1; off >>= 1) {
        a0 += __shfl_xor(a0, off);
        a1 += __shfl_xor(a1, off);
        a2 += __shfl_xor(a2, off);
        a3 += __shfl_xor(a3, off);
    }
    if (l == 0) {
        int e = 0; float best = a0;
        if (a1 > best) { best = a1; e = 1; }
        if (a2 > best) { best = a2; e = 2; }
        if (a3 > best) { best = a3; e = 3; }
        expert_id[n * 1024 + b] = e;
        atomicAdd(&counts[n * 4 + e], 1);
    }
}

// ---------------------------------------------------------------- scatter
__global__ __launch_bounds__(1024) void scatter_kernel(
    const int* __restrict__ expert_id, const int* __restrict__ counts,
    int* __restrict__ row_base, int* __restrict__ rows)
{
    __shared__ int cur[4];
    int n = blockIdx.x, tid = threadIdx.x;
    if (tid == 0) {
        int c0 = counts[n * 4 + 0], c1 = counts[n * 4 + 1], c2 = counts[n * 4 + 2];
        cur[0] = 0; cur[1] = c0; cur[2] = c0 + c1; cur[3] = c0 + c1 + c2;
        row_base[n * 4 + 0] = cur[0]; row_base[n * 4 + 1] = cur[1];
        row_base[n * 4 + 2] = cur[2]; row_base[n * 4 + 3] = cur[3];
    }
    __syncthreads();
    int e = expert_id[n * 1024 + tid];
    int pos = atomicAdd(&cur[e], 1);
    rows[n * 1024 + pos] = tid;
}

// ---------------------------------------------------------------- transpose + bf16
// src fp32 [e][K][N] -> dst bf16 [e][N][K]. 64x64 tiles via LDS.
__global__ __launch_bounds__(256) void transpose_kernel(
    const float* __restrict__ src, __bf16* __restrict__ dst, int K, int N)
{
    __shared__ __bf16 sh[64][68];
    const int e = blockIdx.y;
    const int ntiles = N >> 6;
    const int kt = blockIdx.x / ntiles, nt = blockIdx.x % ntiles;
    const float* s = src + (size_t)e * K * N + (size_t)(kt * 64) * N + nt * 64;
    __bf16* d = dst + (size_t)e * N * K + (size_t)(nt * 64) * K + kt * 64;
    const int tid = threadIdx.x;
    #pragma unroll
    for (int it = 0; it < 4; ++it) {
        int r = (tid >> 4) + it * 16;     // k row in tile
        int c4 = tid & 15;                // n quad
        float4 v = *(const float4*)(s + (size_t)r * N + c4 * 4);
        bf16x4 pv = {(__bf16)v.x, (__bf16)v.y, (__bf16)v.z, (__bf16)v.w};
        *(bf16x4*)&sh[r][c4 * 4] = pv;
    }
    __syncthreads();
    #pragma unroll
    for (int it = 0; it < 4; ++it) {
        int flat = tid + it * 256;
        int nn = flat >> 4, k4 = flat & 15;
        bf16x4 ov = {sh[k4 * 4 + 0][nn], sh[k4 * 4 + 1][nn],
                     sh[k4 * 4 + 2][nn], sh[k4 * 4 + 3][nn]};
        *(bf16x4*)(d + (size_t)nn * K + k4 * 4) = ov;
    }
}

// ---------------------------------------------------------------- grouped GEMM
// C[128,128] per block, BK=64, 4 waves each 64x64 (4x4 frags of 16x16x32 bf16 MFMA).
// A: [1024][K] bf16 (gathered via rows[] for GEMM1, compact rows for GEMM2).
// Bt: [4][N][K] bf16 (N-major). LDS tiles XOR-swizzled (c16 ^= row&7) -> conflict-free.
template <int K, int N, bool GATHER, bool RELU, bool OUTBF>
__global__ __launch_bounds__(256) void moe_gemm_kernel(
    const __bf16* __restrict__ A, const __bf16* __restrict__ Bt,
    const float* __restrict__ bias, const int* __restrict__ rows,
    const int* __restrict__ counts, const int* __restrict__ row_base,
    __bf16* __restrict__ outB, float* __restrict__ outF)
{
    const int e = blockIdx.y >> 3, mt = blockIdx.y & 7;
    const int cnt = counts[e];
    const int row0 = mt * 128;
    if (row0 >= cnt) return;
    const int rbase = row_base[e];
    const int valid = min(128, cnt - row0);
    const int n0 = blockIdx.x * 128;

    __shared__ alignas(16) __bf16 As[128 * 64];
    __shared__ alignas(16) __bf16 Bs[128 * 64];

    const int tid = threadIdx.x;
    const int l = tid & 63, w = tid >> 6;
    const int wr = w >> 1, wc = w & 1;

    const __bf16* aptr[4];
    const __bf16* bptr[4];
    int woff[4];
    #pragma unroll
    for (int i = 0; i < 4; ++i) {
        int flat = tid + i * 256;
        int r = flat >> 3, c = flat & 7;
        int rr = rbase + row0 + min(r, valid - 1);
        int ga = GATHER ? rows[rr] : rr;
        aptr[i] = A + (size_t)ga * K + c * 8;
        bptr[i] = Bt + (size_t)e * N * K + (size_t)(n0 + r) * K + c * 8;
        woff[i] = r * 64 + ((c ^ (r & 7)) * 8);
    }

    f32x4 acc[4][4];
    f32x4 zero = {0.f, 0.f, 0.f, 0.f};
    #pragma unroll
    for (int mi = 0; mi < 4; ++mi)
        #pragma unroll
        for (int ni = 0; ni < 4; ++ni) acc[mi][ni] = zero;

    bf16x8 av[4], bv[4], avn[4], bvn[4];
    #pragma unroll
    for (int i = 0; i < 4; ++i) { av[i] = *(const bf16x8*)aptr[i]; bv[i] = *(const bf16x8*)bptr[i]; }

    for (int k0 = 0; k0 < K; k0 += 64) {
        __syncthreads();
        #pragma unroll
        for (int i = 0; i < 4; ++i) {
            *(bf16x8*)(As + woff[i]) = av[i];
            *(bf16x8*)(Bs + woff[i]) = bv[i];
        }
        if (k0 + 64 < K) {
            #pragma unroll
            for (int i = 0; i < 4; ++i) {
                aptr[i] += 64; bptr[i] += 64;
                avn[i] = *(const bf16x8*)aptr[i];
                bvn[i] = *(const bf16x8*)bptr[i];
            }
        }
        __syncthreads();
        #pragma unroll
        for (int kk = 0; kk < 2; ++kk) {
            bf16x8 af[4], bfv[4];
            #pragma unroll
            for (int mi = 0; mi < 4; ++mi) {
                int row = wr * 64 + mi * 16 + (l & 15);
                int c16 = (kk * 4 + (l >> 4)) ^ (row & 7);
                af[mi] = *(const bf16x8*)(As + row * 64 + c16 * 8);
            }
            #pragma unroll
            for (int ni = 0; ni < 4; ++ni) {
                int row = wc * 64 + ni * 16 + (l & 15);
                int c16 = (kk * 4 + (l >> 4)) ^ (row & 7);
                bfv[ni] = *(const bf16x8*)(Bs + row * 64 + c16 * 8);
            }
            #pragma unroll
            for (int mi = 0; mi < 4; ++mi)
                #pragma unroll
                for (int ni = 0; ni < 4; ++ni)
                    acc[mi][ni] = __builtin_amdgcn_mfma_f32_16x16x32_bf16(
                        af[mi], bfv[ni], acc[mi][ni], 0, 0, 0);
        }
        #pragma unroll
        for (int i = 0; i < 4; ++i) { av[i] = avn[i]; bv[i] = bvn[i]; }
    }

    const int lrow = l >> 4, lcol = l & 15;
    #pragma unroll
    for (int ni = 0; ni < 4; ++ni) {
        int col = n0 + wc * 64 + ni * 16 + lcol;
        float bval = bias[e * N + col];
        #pragma unroll
        for (int mi = 0; mi < 4; ++mi) {
            #pragma unroll
            for (int j = 0; j < 4; ++j) {
                int rt = wr * 64 + mi * 16 + lrow * 4 + j;
                if (rt < valid) {
                    float v = acc[mi][ni][j] + bval;
                    if (RELU) v = fmaxf(v, 0.f);
                    int crow = rbase + row0 + rt;
                    if (OUTBF) {
                        outB[(size_t)crow * N + col] = (__bf16)v;
                    } else {
                        int tokid = rows[crow];
                        outF[(size_t)tokid * N + col] = v;
                    }
                }
            }
        }
    }
}

// ---------------------------------------------------------------- poly + sigmoid
__global__ __launch_bounds__(256) void poly_kernel(
    const float* __restrict__ input, const float* __restrict__ moe,
    float* __restrict__ out)
{
    const int b = blockIdx.x, tid = threadIdx.x;
    const size_t pb = (size_t)b * 1024 + (size_t)tid * 4;
    float4 f0 = *(const float4*)(moe + (size_t)(0 * 1024 + b) * 1024 + tid * 4); // transform
    float4 f1 = *(const float4*)(moe + (size_t)(1 * 1024 + b) * 1024 + tid * 4); // add
    float4 f2 = *(const float4*)(moe + (size_t)(2 * 1024 + b) * 1024 + tid * 4); // quad
    float4 f3 = *(const float4*)(moe + (size_t)(3 * 1024 + b) * 1024 + tid * 4); // cubic
    float4 f4 = *(const float4*)(moe + (size_t)(4 * 1024 + b) * 1024 + tid * 4); // fourth
    (void)pb;
    const float4* ipv = (const float4*)(input + (size_t)b * 10240);
    float4* opv = (float4*)(out + (size_t)b * 10240);
    #pragma unroll
    for (int t = 0; t < 10; ++t) {
        float4 x = ipv[t * 256 + tid];
        float4 r;
        {
            float i2 = x.x * x.x;
            float p = i2 * (i2 * f4.x + x.x * f3.x + f2.x) + x.x * f0.x + f1.x;
            r.x = 1.f / (1.f + __expf(-p));
        }
        {
            float i2 = x.y * x.y;
            float p = i2 * (i2 * f4.y + x.y * f3.y + f2.y) + x.y * f0.y + f1.y;
            r.y = 1.f / (1.f + __expf(-p));
        }
        {
            float i2 = x.z * x.z;
            float p = i2 * (i2 * f4.z + x.z * f3.z + f2.z) + x.z * f0.z + f1.z;
            r.z = 1.f / (1.f + __expf(-p));
        }
        {
            float i2 = x.w * x.w;
            float p = i2 * (i2 * f4.w + x.w * f3.w + f2.w) + x.w * f0.w + f1.w;
            r.w = 1.f / (1.f + __expf(-p));
        }
        opv[t * 256 + tid] = r;
    }
}

// ---------------------------------------------------------------- loss
__global__ void loss_kernel(const int* __restrict__ counts, float* __restrict__ out_loss)
{
    if (threadIdx.x == 0 && blockIdx.x == 0) {
        float total = 0.f;
        for (int n = 0; n < NMOE; ++n) {
            const float m = 256.f;
            float var = 0.f;
            for (int e = 0; e < 4; ++e) {
                float d = (float)counts[n * 4 + e] - m;
                var += d * d;
            }
            var *= (1.f / 3.f);                       // ddof=1
            float cv2 = var / (m * m + 1e-10f);
            total += 2.f * cv2 * 1e-2f;               // importance == load == counts
        }
        *out_loss = total;
    }
}

// ---------------------------------------------------------------- launch
extern "C" void kernel_launch(void* const* d_in, const int* in_sizes, int n_in,
                              void* d_out, int out_size, void* d_ws, size_t ws_size,
                              hipStream_t stream)
{
    const float* input = (const float*)d_in[0];
    const float* c1w   = (const float*)d_in[1];
    const float* c1b   = (const float*)d_in[2];
    const float* c2w   = (const float*)d_in[3];
    const float* c2b   = (const float*)d_in[4];
    const float* wgate = (const float*)d_in[5];
    const float* w1    = (const float*)d_in[6];
    const float* b1    = (const float*)d_in[7];
    const float* w2    = (const float*)d_in[8];
    const float* b2    = (const float*)d_in[9];
    float* out = (float*)d_out;

    char* ws = (char*)d_ws;
    float*  tok_f32   = (float*)(ws + 0);                 //  4 MB
    __bf16* tok_bf16  = (__bf16*)(ws + 4194304);          //  2 MB
    __bf16* wt        = (__bf16*)(ws + 6291456);          // 16.78 MB (per-module, reused)
    __bf16* h         = (__bf16*)(ws + 23068672);         //  4.19 MB (per-module, reused)
    float*  moe_out   = (float*)(ws + 27262976);          // 20.97 MB [5][1024][1024]
    int*    rows      = (int*)(ws + 48234496);            // [5][1024]
    int*    expert_id = (int*)(ws + 48254976);            // [5][1024]
    int*    counts    = (int*)(ws + 48275456);            // [5][4]
    int*    row_base  = (int*)(ws + 48275536);            // [5][4]

    hipMemsetAsync(counts, 0, NMOE * NEXP * sizeof(int), stream);

    conv_tok_kernel<<<1024, 256, 0, stream>>>(input, c1w, c1b, c2w, c2b, tok_f32, tok_bf16);
    gating_kernel<<<1280, 256, 0, stream>>>(tok_f32, wgate, expert_id, counts);
    scatter_kernel<<<5, 1024, 0, stream>>>(expert_id, counts, row_base, rows);

    for (int n = 0; n < NMOE; ++n) {
        transpose_kernel<<<dim3(512, 4), 256, 0, stream>>>(
            w1 + (size_t)n * 4 * 1024 * 2048, wt, 1024, 2048);
        moe_gemm_kernel<1024, 2048, true, true, true><<<dim3(16, 32), 256, 0, stream>>>(
            tok_bf16, wt, b1 + (size_t)n * 4 * 2048, rows + n * 1024,
            counts + n * 4, row_base + n * 4, h, nullptr);
        transpose_kernel<<<dim3(512, 4), 256, 0, stream>>>(
            w2 + (size_t)n * 4 * 2048 * 1024, wt, 2048, 1024);
        moe_gemm_kernel<2048, 1024, false, false, false><<<dim3(8, 32), 256, 0, stream>>>(
            h, wt, b2 + (size_t)n * 4 * 1024, rows + n * 1024,
            counts + n * 4, row_base + n * 4, nullptr, moe_out + (size_t)n * 1024 * 1024);
    }

    poly_kernel<<<1024, 256, 0, stream>>>(input, moe_out, out);
    loss_kernel<<<1, 64, 0, stream>>>(counts, out + 10485760);
}

// Round 3
// 597.543 us; speedup vs baseline: 1.2319x; 1.2319x over previous
//
#include <hip/hip_runtime.h>
#include <hip/hip_bf16.h>

// ED_Fourth_MOE round 3: BISECTION — round-1 conv (verbatim, proven tok bits) +
// round-2 fused-transpose GEMM with all-modules-one-grid (algebra proven).

typedef __bf16 bf16x8 __attribute__((ext_vector_type(8)));
typedef __bf16 bf16x4 __attribute__((ext_vector_type(4)));
typedef __bf16 bf16x2 __attribute__((ext_vector_type(2)));
typedef float f32x4 __attribute__((ext_vector_type(4)));

#define NMOE 5
#define NEXP 4

// ---------------------------------------------------------------- conv fused (round-1 verbatim)
__global__ __launch_bounds__(256) void conv_tok_kernel(
    const float* __restrict__ input, const float* __restrict__ c1w,
    const float* __restrict__ c1b, const float* __restrict__ c2w,
    const float* __restrict__ c2b, float* __restrict__ tok_f32,
    __bf16* __restrict__ tok_bf16)
{
    __shared__ float in_s[10][34][34];
    __shared__ float P[34][34];
    const int b = blockIdx.x, tid = threadIdx.x;

    float* ls = &in_s[0][0][0];
    for (int i = tid; i < 10 * 34 * 34; i += 256) ls[i] = 0.f;
    for (int i = tid; i < 34 * 34; i += 256) (&P[0][0])[i] = 0.f;
    __syncthreads();

    const float* ip = input + (size_t)b * 10240;
    for (int i = tid; i < 2560; i += 256) {
        int t = i >> 8, rem = i & 255;
        int h = rem >> 3, w4 = rem & 7;
        float4 v = ((const float4*)ip)[i];
        float* dst = &in_s[t][h + 1][w4 * 4 + 1];
        dst[0] = v.x; dst[1] = v.y; dst[2] = v.z; dst[3] = v.w;
    }
    __syncthreads();

    const int wcol = tid & 31;
    const int r0 = (tid >> 5) * 4;
    const float c2bias = c2b[0];
    float tk0 = c2bias, tk1 = c2bias, tk2 = c2bias, tk3 = c2bias;

    for (int c = 0; c < 10; ++c) {
        float w1l[27];
        #pragma unroll
        for (int i = 0; i < 27; ++i) w1l[i] = c1w[c * 27 + i];
        const float c1bias = c1b[c];
        for (int t = 0; t < 10; ++t) {
            float a0 = c1bias, a1 = c1bias, a2 = c1bias, a3 = c1bias;
            #pragma unroll
            for (int dt = 0; dt < 3; ++dt) {
                int ts = t + dt - 1;
                if (ts < 0 || ts >= 10) continue;
                #pragma unroll
                for (int dw = 0; dw < 3; ++dw) {
                    float v0 = in_s[ts][r0 + 0][wcol + dw];
                    float v1 = in_s[ts][r0 + 1][wcol + dw];
                    float v2 = in_s[ts][r0 + 2][wcol + dw];
                    float v3 = in_s[ts][r0 + 3][wcol + dw];
                    float v4 = in_s[ts][r0 + 4][wcol + dw];
                    float v5 = in_s[ts][r0 + 5][wcol + dw];
                    float u0 = w1l[dt * 9 + 0 + dw];
                    float u1 = w1l[dt * 9 + 3 + dw];
                    float u2 = w1l[dt * 9 + 6 + dw];
                    a0 += u0 * v0 + u1 * v1 + u2 * v2;
                    a1 += u0 * v1 + u1 * v2 + u2 * v3;
                    a2 += u0 * v2 + u1 * v3 + u2 * v4;
                    a3 += u0 * v3 + u1 * v4 + u2 * v5;
                }
            }
            __syncthreads();   // previous plane's conv2 reads done
            P[r0 + 1][wcol + 1] = fmaxf(a0, 0.f);
            P[r0 + 2][wcol + 1] = fmaxf(a1, 0.f);
            P[r0 + 3][wcol + 1] = fmaxf(a2, 0.f);
            P[r0 + 4][wcol + 1] = fmaxf(a3, 0.f);
            __syncthreads();
            const int wb = (c * 10 + t) * 9;
            #pragma unroll
            for (int dw = 0; dw < 3; ++dw) {
                float q0 = P[r0 + 0][wcol + dw];
                float q1 = P[r0 + 1][wcol + dw];
                float q2 = P[r0 + 2][wcol + dw];
                float q3 = P[r0 + 3][wcol + dw];
                float q4 = P[r0 + 4][wcol + dw];
                float q5 = P[r0 + 5][wcol + dw];
                float u0 = c2w[wb + 0 + dw];
                float u1 = c2w[wb + 3 + dw];
                float u2 = c2w[wb + 6 + dw];
                tk0 += u0 * q0 + u1 * q1 + u2 * q2;
                tk1 += u0 * q1 + u1 * q2 + u2 * q3;
                tk2 += u0 * q2 + u1 * q3 + u2 * q4;
                tk3 += u0 * q3 + u1 * q4 + u2 * q5;
            }
        }
    }
    float o0 = fmaxf(tk0, 0.f), o1 = fmaxf(tk1, 0.f);
    float o2 = fmaxf(tk2, 0.f), o3 = fmaxf(tk3, 0.f);
    size_t base = (size_t)b * 1024 + (size_t)r0 * 32 + wcol;
    tok_f32[base] = o0; tok_f32[base + 32] = o1;
    tok_f32[base + 64] = o2; tok_f32[base + 96] = o3;
    tok_bf16[base] = (__bf16)o0; tok_bf16[base + 32] = (__bf16)o1;
    tok_bf16[base + 64] = (__bf16)o2; tok_bf16[base + 96] = (__bf16)o3;
}

// ---------------------------------------------------------------- gating
__global__ __launch_bounds__(256) void gating_kernel(
    const float* __restrict__ tok, const float* __restrict__ w_gate,
    int* __restrict__ expert_id, int* __restrict__ counts)
{
    int gw = blockIdx.x * 4 + (threadIdx.x >> 6);
    int l = threadIdx.x & 63;
    int n = gw >> 10, b = gw & 1023;
    const float* trow = tok + (size_t)b * 1024;
    const float* wg = w_gate + (size_t)n * 4096;
    float a0 = 0.f, a1 = 0.f, a2 = 0.f, a3 = 0.f;
    #pragma unroll
    for (int i = 0; i < 16; ++i) {
        int d = i * 64 + l;
        float tv = trow[d];
        float4 g4 = *(const float4*)(wg + d * 4);
        a0 += tv * g4.x; a1 += tv * g4.y; a2 += tv * g4.z; a3 += tv * g4.w;
    }
    #pragma unroll
    for (int off = 32; off >= 1; off >>= 1) {
        a0 += __shfl_xor(a0, off);
        a1 += __shfl_xor(a1, off);
        a2 += __shfl_xor(a2, off);
        a3 += __shfl_xor(a3, off);
    }
    if (l == 0) {
        int e = 0; float best = a0;
        if (a1 > best) { best = a1; e = 1; }
        if (a2 > best) { best = a2; e = 2; }
        if (a3 > best) { best = a3; e = 3; }
        expert_id[n * 1024 + b] = e;
        atomicAdd(&counts[n * 4 + e], 1);
    }
}

// ---------------------------------------------------------------- scatter
__global__ __launch_bounds__(1024) void scatter_kernel(
    const int* __restrict__ expert_id, const int* __restrict__ counts,
    int* __restrict__ row_base, int* __restrict__ rows)
{
    __shared__ int cur[4];
    int n = blockIdx.x, tid = threadIdx.x;
    if (tid == 0) {
        int c0 = counts[n * 4 + 0], c1 = counts[n * 4 + 1], c2 = counts[n * 4 + 2];
        cur[0] = 0; cur[1] = c0; cur[2] = c0 + c1; cur[3] = c0 + c1 + c2;
        row_base[n * 4 + 0] = cur[0]; row_base[n * 4 + 1] = cur[1];
        row_base[n * 4 + 2] = cur[2]; row_base[n * 4 + 3] = cur[3];
    }
    __syncthreads();
    int e = expert_id[n * 1024 + tid];
    int pos = atomicAdd(&cur[e], 1);
    rows[n * 1024 + pos] = tid;
}

// ---------------------------------------------------------------- grouped GEMM (all modules)
// grid y = mod*32 + e*8 + mt (160), x = n-tiles. C tile 128x128, BK=64, 4 waves.
// A: bf16 k-contiguous (gathered for GEMM1). B: fp32 [grp][K][N] — transposed+converted
// to bf16 during LDS staging. As swizzle: chunk^(r&7). Bs swizzle: chunk^g(n), g(n)=(n^(n>>3))&7.
template <int K, int N, bool GATHER, bool RELU, bool OUTBF>
__global__ __launch_bounds__(256) void moe_gemm_kernel(
    const __bf16* __restrict__ Abase, const float* __restrict__ Bsrc,
    const float* __restrict__ bias, const int* __restrict__ rows_all,
    const int* __restrict__ counts_all, const int* __restrict__ rowbase_all,
    __bf16* __restrict__ outB, float* __restrict__ outF)
{
    const int gy = blockIdx.y;
    const int mod = gy >> 5, rem = gy & 31;
    const int e = rem >> 3, mt = rem & 7;
    const int grp = mod * 4 + e;
    const int cnt = counts_all[grp];
    const int row0 = mt * 128;
    if (row0 >= cnt) return;
    const int rbase = rowbase_all[grp];
    const int valid = min(128, cnt - row0);
    const int n0 = blockIdx.x * 128;
    const int* rows = rows_all + mod * 1024;

    __shared__ alignas(16) __bf16 As[128 * 64];
    __shared__ alignas(16) __bf16 Bs[128 * 64];

    const int tid = threadIdx.x;
    const int l = tid & 63, w = tid >> 6;
    const int wr = w >> 1, wc = w & 1;

    // ---- A staging setup
    const __bf16* aptr[4];
    int woffA[4];
    const __bf16* abase2 = GATHER ? Abase : (Abase + (size_t)mod * 1024 * (size_t)K);
    #pragma unroll
    for (int i = 0; i < 4; ++i) {
        int flat = tid + i * 256;
        int rr = flat >> 3, cc = flat & 7;
        int ri = rbase + row0 + min(rr, valid - 1);
        int ga = GATHER ? rows[ri] : ri;
        aptr[i] = abase2 + (size_t)ga * K + cc * 8;
        woffA[i] = rr * 64 + ((cc ^ (rr & 7)) * 8);
    }
    // ---- B staging setup: unit i covers k-rows (2rp,2rp+1) x n-cols 4cq..4cq+3
    const float* bp0 = Bsrc + (size_t)grp * K * N + n0;
    const float* bptr[4][2];
    int boff[4], bx[4];
    #pragma unroll
    for (int i = 0; i < 4; ++i) {
        int u = tid + i * 256;
        int rp = u >> 5, cq = u & 31;
        bptr[i][0] = bp0 + (size_t)(2 * rp) * N + 4 * cq;
        bptr[i][1] = bp0 + (size_t)(2 * rp + 1) * N + 4 * cq;
        boff[i] = (4 * cq) * 64 + ((rp & 3) << 1);
        bx[i] = (rp >> 2) ^ (4 * (cq & 1)) ^ ((cq >> 1) & 7);
    }

    f32x4 acc[4][4];
    f32x4 zero = {0.f, 0.f, 0.f, 0.f};
    #pragma unroll
    for (int mi = 0; mi < 4; ++mi)
        #pragma unroll
        for (int ni = 0; ni < 4; ++ni) acc[mi][ni] = zero;

    bf16x8 av[4], avn[4];
    f32x4 bv[4][2], bvn[4][2];
    #pragma unroll
    for (int i = 0; i < 4; ++i) {
        av[i] = *(const bf16x8*)aptr[i];
        bv[i][0] = *(const f32x4*)bptr[i][0];
        bv[i][1] = *(const f32x4*)bptr[i][1];
    }

    for (int k0 = 0; k0 < K; k0 += 64) {
        __syncthreads();
        #pragma unroll
        for (int i = 0; i < 4; ++i) {
            *(bf16x8*)(As + woffA[i]) = av[i];
            #pragma unroll
            for (int q = 0; q < 4; ++q) {
                bf16x2 val = {(__bf16)bv[i][0][q], (__bf16)bv[i][1][q]};
                *(bf16x2*)(Bs + boff[i] + q * 64 + ((bx[i] ^ q) << 3)) = val;
            }
        }
        if (k0 + 64 < K) {
            #pragma unroll
            for (int i = 0; i < 4; ++i) {
                aptr[i] += 64;
                bptr[i][0] += (size_t)64 * N;
                bptr[i][1] += (size_t)64 * N;
                avn[i] = *(const bf16x8*)aptr[i];
                bvn[i][0] = *(const f32x4*)bptr[i][0];
                bvn[i][1] = *(const f32x4*)bptr[i][1];
            }
        }
        __syncthreads();
        #pragma unroll
        for (int kk = 0; kk < 2; ++kk) {
            bf16x8 af[4], bfv[4];
            #pragma unroll
            for (int mi = 0; mi < 4; ++mi) {
                int row = wr * 64 + mi * 16 + (l & 15);
                int cc = (kk * 4 + (l >> 4)) ^ (row & 7);
                af[mi] = *(const bf16x8*)(As + row * 64 + cc * 8);
            }
            #pragma unroll
            for (int ni = 0; ni < 4; ++ni) {
                int nrow = wc * 64 + ni * 16 + (l & 15);
                int gg = (nrow ^ (nrow >> 3)) & 7;
                int cc = (kk * 4 + (l >> 4)) ^ gg;
                bfv[ni] = *(const bf16x8*)(Bs + nrow * 64 + cc * 8);
            }
            #pragma unroll
            for (int mi = 0; mi < 4; ++mi)
                #pragma unroll
                for (int ni = 0; ni < 4; ++ni)
                    acc[mi][ni] = __builtin_amdgcn_mfma_f32_16x16x32_bf16(
                        af[mi], bfv[ni], acc[mi][ni], 0, 0, 0);
        }
        #pragma unroll
        for (int i = 0; i < 4; ++i) {
            av[i] = avn[i];
            bv[i][0] = bvn[i][0];
            bv[i][1] = bvn[i][1];
        }
    }

    const int lrow = l >> 4, lcol = l & 15;
    #pragma unroll
    for (int ni = 0; ni < 4; ++ni) {
        int col = n0 + wc * 64 + ni * 16 + lcol;
        float bval = bias[(size_t)grp * N + col];
        #pragma unroll
        for (int mi = 0; mi < 4; ++mi) {
            #pragma unroll
            for (int j = 0; j < 4; ++j) {
                int rt = wr * 64 + mi * 16 + lrow * 4 + j;
                if (rt < valid) {
                    float v = acc[mi][ni][j] + bval;
                    if (RELU) v = fmaxf(v, 0.f);
                    int crow = rbase + row0 + rt;
                    if (OUTBF) {
                        outB[((size_t)mod * 1024 + crow) * N + col] = (__bf16)v;
                    } else {
                        int tokid = rows[crow];
                        outF[((size_t)mod * 1024 + tokid) * N + col] = v;
                    }
                }
            }
        }
    }
}

// ---------------------------------------------------------------- poly + sigmoid
__global__ __launch_bounds__(256) void poly_kernel(
    const float* __restrict__ input, const float* __restrict__ moe,
    float* __restrict__ out)
{
    const int b = blockIdx.x, tid = threadIdx.x;
    float4 f0 = *(const float4*)(moe + (size_t)(0 * 1024 + b) * 1024 + tid * 4); // transform
    float4 f1 = *(const float4*)(moe + (size_t)(1 * 1024 + b) * 1024 + tid * 4); // add
    float4 f2 = *(const float4*)(moe + (size_t)(2 * 1024 + b) * 1024 + tid * 4); // quad
    float4 f3 = *(const float4*)(moe + (size_t)(3 * 1024 + b) * 1024 + tid * 4); // cubic
    float4 f4 = *(const float4*)(moe + (size_t)(4 * 1024 + b) * 1024 + tid * 4); // fourth
    const float4* ipv = (const float4*)(input + (size_t)b * 10240);
    float4* opv = (float4*)(out + (size_t)b * 10240);
    #pragma unroll
    for (int t = 0; t < 10; ++t) {
        float4 x = ipv[t * 256 + tid];
        float4 r;
        {
            float i2 = x.x * x.x;
            float p = i2 * (i2 * f4.x + x.x * f3.x + f2.x) + x.x * f0.x + f1.x;
            r.x = 1.f / (1.f + __expf(-p));
        }
        {
            float i2 = x.y * x.y;
            float p = i2 * (i2 * f4.y + x.y * f3.y + f2.y) + x.y * f0.y + f1.y;
            r.y = 1.f / (1.f + __expf(-p));
        }
        {
            float i2 = x.z * x.z;
            float p = i2 * (i2 * f4.z + x.z * f3.z + f2.z) + x.z * f0.z + f1.z;
            r.z = 1.f / (1.f + __expf(-p));
        }
        {
            float i2 = x.w * x.w;
            float p = i2 * (i2 * f4.w + x.w * f3.w + f2.w) + x.w * f0.w + f1.w;
            r.w = 1.f / (1.f + __expf(-p));
        }
        opv[t * 256 + tid] = r;
    }
}

// ---------------------------------------------------------------- loss
__global__ void loss_kernel(const int* __restrict__ counts, float* __restrict__ out_loss)
{
    if (threadIdx.x == 0 && blockIdx.x == 0) {
        float total = 0.f;
        for (int n = 0; n < NMOE; ++n) {
            const float m = 256.f;
            float var = 0.f;
            for (int e = 0; e < 4; ++e) {
                float d = (float)counts[n * 4 + e] - m;
                var += d * d;
            }
            var *= (1.f / 3.f);                       // ddof=1
            float cv2 = var / (m * m + 1e-10f);
            total += 2.f * cv2 * 1e-2f;               // importance == load == counts
        }
        *out_loss = total;
    }
}

// ---------------------------------------------------------------- launch
extern "C" void kernel_launch(void* const* d_in, const int* in_sizes, int n_in,
                              void* d_out, int out_size, void* d_ws, size_t ws_size,
                              hipStream_t stream)
{
    (void)in_sizes; (void)n_in; (void)out_size; (void)ws_size;
    const float* input = (const float*)d_in[0];
    const float* c1w   = (const float*)d_in[1];
    const float* c1b   = (const float*)d_in[2];
    const float* c2w   = (const float*)d_in[3];
    const float* c2b   = (const float*)d_in[4];
    const float* wgate = (const float*)d_in[5];
    const float* w1    = (const float*)d_in[6];
    const float* b1    = (const float*)d_in[7];
    const float* w2    = (const float*)d_in[8];
    const float* b2    = (const float*)d_in[9];
    float* out = (float*)d_out;

    char* ws = (char*)d_ws;
    float*  tok_f32   = (float*)(ws + 0);                 //  4 MB
    __bf16* tok_bf16  = (__bf16*)(ws + 4194304);          //  2 MB
    __bf16* h         = (__bf16*)(ws + 6291456);          // 20.97 MB [5][1024][2048] bf16
    float*  moe_out   = (float*)(ws + 27262976);          // 20.97 MB [5][1024][1024] f32
    int*    rows      = (int*)(ws + 48234496);            // [5][1024]
    int*    expert_id = (int*)(ws + 48254976);            // [5][1024]
    int*    counts    = (int*)(ws + 48275456);            // [5][4]
    int*    row_base  = (int*)(ws + 48275536);            // [5][4]

    hipMemsetAsync(counts, 0, NMOE * NEXP * sizeof(int), stream);

    conv_tok_kernel<<<1024, 256, 0, stream>>>(input, c1w, c1b, c2w, c2b, tok_f32, tok_bf16);
    gating_kernel<<<1280, 256, 0, stream>>>(tok_f32, wgate, expert_id, counts);
    scatter_kernel<<<5, 1024, 0, stream>>>(expert_id, counts, row_base, rows);

    moe_gemm_kernel<1024, 2048, true, true, true><<<dim3(16, 160), 256, 0, stream>>>(
        tok_bf16, w1, b1, rows, counts, row_base, h, nullptr);
    moe_gemm_kernel<2048, 1024, false, false, false><<<dim3(8, 160), 256, 0, stream>>>(
        h, w2, b2, rows, counts, row_base, nullptr, moe_out);

    poly_kernel<<<1024, 256, 0, stream>>>(input, moe_out, out);
    loss_kernel<<<1, 64, 0, stream>>>(counts, out + 10485760);
}

// Round 4
// 593.073 us; speedup vs baseline: 1.2412x; 1.0075x over previous
//
#include <hip/hip_runtime.h>
#include <hip/hip_bf16.h>

// ED_Fourth_MOE round 4:
//  - conv: rolling 4-plane LDS ring (27.8 KB, 4 blocks/CU) + LDS weight cache.
//    ALL arithmetic statements verbatim from round-1 (bit-exact tok — gating argmax
//    is numerically fragile; round-2 proved reassociation flips experts).
//  - GEMM: BM=256 (512 thr, 8 waves) halves fp32 weight re-reads; staging/swizzle
//    formulas verbatim from proven round-3 kernel.

typedef __bf16 bf16x8 __attribute__((ext_vector_type(8)));
typedef __bf16 bf16x4 __attribute__((ext_vector_type(4)));
typedef __bf16 bf16x2 __attribute__((ext_vector_type(2)));
typedef float f32x4 __attribute__((ext_vector_type(4)));

#define NMOE 5
#define NEXP 4

// ---------------------------------------------------------------- conv fused
// One block per image, 256 threads: wcol = tid&31, rows r0..r0+3 (r0=(tid>>5)*4).
// Ring inQ[4] holds planes t-1,t,t+1 (+prefetch t+2); re-staged per c (L2-hit).
__global__ __launch_bounds__(256) void conv_tok_kernel(
    const float* __restrict__ input, const float* __restrict__ c1w,
    const float* __restrict__ c1b, const float* __restrict__ c2w,
    const float* __restrict__ c2b, float* __restrict__ tok_f32,
    __bf16* __restrict__ tok_bf16)
{
    __shared__ float inQ[4][34][34];
    __shared__ float P[34][34];
    __shared__ float c2w_s[900];
    __shared__ float c1w_s[270];
    const int b = blockIdx.x, tid = threadIdx.x;

    float* q = &inQ[0][0][0];
    for (int i = tid; i < 4 * 34 * 34; i += 256) q[i] = 0.f;
    for (int i = tid; i < 34 * 34; i += 256) (&P[0][0])[i] = 0.f;
    for (int i = tid; i < 900; i += 256) c2w_s[i] = c2w[i];
    for (int i = tid; i < 270; i += 256) c1w_s[i] = c1w[i];
    __syncthreads();

    const float* ip = input + (size_t)b * 10240;
    const int wcol = tid & 31;
    const int r0 = (tid >> 5) * 4;
    const int h1 = (tid >> 3) + 1;       // staging row (1..32)
    const int w4 = (tid & 7) * 4 + 1;    // staging col base (1,5,..,29)

    const float c2bias = c2b[0];
    float tk0 = c2bias, tk1 = c2bias, tk2 = c2bias, tk3 = c2bias;

    for (int c = 0; c < 10; ++c) {
        float w1l[27];
        #pragma unroll
        for (int i = 0; i < 27; ++i) w1l[i] = c1w_s[c * 27 + i];
        const float c1bias = c1b[c];

        // prologue: stage planes 0,1 (safe: all prev-c inQ reads ended before its
        // t=9 second barrier, which every thread has passed before reaching here)
        {
            float4 s0 = *(const float4*)(ip + 0 * 1024 + tid * 4);
            float4 s1 = *(const float4*)(ip + 1 * 1024 + tid * 4);
            float* d0 = &inQ[0][h1][w4];
            d0[0] = s0.x; d0[1] = s0.y; d0[2] = s0.z; d0[3] = s0.w;
            float* d1 = &inQ[1][h1][w4];
            d1[0] = s1.x; d1[1] = s1.y; d1[2] = s1.z; d1[3] = s1.w;
        }

        for (int t = 0; t < 10; ++t) {
            const bool hn = (t + 2 <= 9);
            float4 nv;
            if (hn) nv = *(const float4*)(ip + (t + 2) * 1024 + tid * 4);

            __syncthreads();   // plane t+1 staged & visible; prev-iter P reads done

            float a0 = c1bias, a1 = c1bias, a2 = c1bias, a3 = c1bias;
            #pragma unroll
            for (int dt = 0; dt < 3; ++dt) {
                int ts = t + dt - 1;
                if (ts < 0 || ts >= 10) continue;
                const float (*pl)[34] = inQ[ts & 3];
                #pragma unroll
                for (int dw = 0; dw < 3; ++dw) {
                    float v0 = pl[r0 + 0][wcol + dw];
                    float v1 = pl[r0 + 1][wcol + dw];
                    float v2 = pl[r0 + 2][wcol + dw];
                    float v3 = pl[r0 + 3][wcol + dw];
                    float v4 = pl[r0 + 4][wcol + dw];
                    float v5 = pl[r0 + 5][wcol + dw];
                    float u0 = w1l[dt * 9 + 0 + dw];
                    float u1 = w1l[dt * 9 + 3 + dw];
                    float u2 = w1l[dt * 9 + 6 + dw];
                    a0 += u0 * v0 + u1 * v1 + u2 * v2;
                    a1 += u0 * v1 + u1 * v2 + u2 * v3;
                    a2 += u0 * v2 + u1 * v3 + u2 * v4;
                    a3 += u0 * v3 + u1 * v4 + u2 * v5;
                }
            }
            P[r0 + 1][wcol + 1] = fmaxf(a0, 0.f);
            P[r0 + 2][wcol + 1] = fmaxf(a1, 0.f);
            P[r0 + 3][wcol + 1] = fmaxf(a2, 0.f);
            P[r0 + 4][wcol + 1] = fmaxf(a3, 0.f);

            __syncthreads();   // P complete; plane-(t+2) slot's old reads done

            if (hn) {
                float* dn = &inQ[(t + 2) & 3][h1][w4];
                dn[0] = nv.x; dn[1] = nv.y; dn[2] = nv.z; dn[3] = nv.w;
            }

            const int wb = (c * 10 + t) * 9;
            #pragma unroll
            for (int dw = 0; dw < 3; ++dw) {
                float q0 = P[r0 + 0][wcol + dw];
                float q1 = P[r0 + 1][wcol + dw];
                float q2 = P[r0 + 2][wcol + dw];
                float q3 = P[r0 + 3][wcol + dw];
                float q4 = P[r0 + 4][wcol + dw];
                float q5 = P[r0 + 5][wcol + dw];
                float u0 = c2w_s[wb + 0 + dw];
                float u1 = c2w_s[wb + 3 + dw];
                float u2 = c2w_s[wb + 6 + dw];
                tk0 += u0 * q0 + u1 * q1 + u2 * q2;
                tk1 += u0 * q1 + u1 * q2 + u2 * q3;
                tk2 += u0 * q2 + u1 * q3 + u2 * q4;
                tk3 += u0 * q3 + u1 * q4 + u2 * q5;
            }
        }
    }
    float o0 = fmaxf(tk0, 0.f), o1 = fmaxf(tk1, 0.f);
    float o2 = fmaxf(tk2, 0.f), o3 = fmaxf(tk3, 0.f);
    size_t base = (size_t)b * 1024 + (size_t)r0 * 32 + wcol;
    tok_f32[base] = o0; tok_f32[base + 32] = o1;
    tok_f32[base + 64] = o2; tok_f32[base + 96] = o3;
    tok_bf16[base] = (__bf16)o0; tok_bf16[base + 32] = (__bf16)o1;
    tok_bf16[base + 64] = (__bf16)o2; tok_bf16[base + 96] = (__bf16)o3;
}

// ---------------------------------------------------------------- gating
__global__ __launch_bounds__(256) void gating_kernel(
    const float* __restrict__ tok, const float* __restrict__ w_gate,
    int* __restrict__ expert_id, int* __restrict__ counts)
{
    int gw = blockIdx.x * 4 + (threadIdx.x >> 6);
    int l = threadIdx.x & 63;
    int n = gw >> 10, b = gw & 1023;
    const float* trow = tok + (size_t)b * 1024;
    const float* wg = w_gate + (size_t)n * 4096;
    float a0 = 0.f, a1 = 0.f, a2 = 0.f, a3 = 0.f;
    #pragma unroll
    for (int i = 0; i < 16; ++i) {
        int d = i * 64 + l;
        float tv = trow[d];
        float4 g4 = *(const float4*)(wg + d * 4);
        a0 += tv * g4.x; a1 += tv * g4.y; a2 += tv * g4.z; a3 += tv * g4.w;
    }
    #pragma unroll
    for (int off = 32; off >= 1; off >>= 1) {
        a0 += __shfl_xor(a0, off);
        a1 += __shfl_xor(a1, off);
        a2 += __shfl_xor(a2, off);
        a3 += __shfl_xor(a3, off);
    }
    if (l == 0) {
        int e = 0; float best = a0;
        if (a1 > best) { best = a1; e = 1; }
        if (a2 > best) { best = a2; e = 2; }
        if (a3 > best) { best = a3; e = 3; }
        expert_id[n * 1024 + b] = e;
        atomicAdd(&counts[n * 4 + e], 1);
    }
}

// ---------------------------------------------------------------- scatter
__global__ __launch_bounds__(1024) void scatter_kernel(
    const int* __restrict__ expert_id, const int* __restrict__ counts,
    int* __restrict__ row_base, int* __restrict__ rows)
{
    __shared__ int cur[4];
    int n = blockIdx.x, tid = threadIdx.x;
    if (tid == 0) {
        int c0 = counts[n * 4 + 0], c1 = counts[n * 4 + 1], c2 = counts[n * 4 + 2];
        cur[0] = 0; cur[1] = c0; cur[2] = c0 + c1; cur[3] = c0 + c1 + c2;
        row_base[n * 4 + 0] = cur[0]; row_base[n * 4 + 1] = cur[1];
        row_base[n * 4 + 2] = cur[2]; row_base[n * 4 + 3] = cur[3];
    }
    __syncthreads();
    int e = expert_id[n * 1024 + tid];
    int pos = atomicAdd(&cur[e], 1);
    rows[n * 1024 + pos] = tid;
}

// ---------------------------------------------------------------- grouped GEMM (BM=256)
// grid y = mod*16 + e*4 + mt (80). C tile 256x128, BK=64, 8 waves (4m x 2n), wave 64x64.
// A: bf16 k-contiguous (gathered for GEMM1). B: fp32 [grp][K][N] transposed+converted
// to bf16 in LDS staging. Swizzles verbatim from proven round-3 kernel.
template <int K, int N, bool GATHER, bool RELU, bool OUTBF>
__global__ __launch_bounds__(512) void moe_gemm_kernel(
    const __bf16* __restrict__ Abase, const float* __restrict__ Bsrc,
    const float* __restrict__ bias, const int* __restrict__ rows_all,
    const int* __restrict__ counts_all, const int* __restrict__ rowbase_all,
    __bf16* __restrict__ outB, float* __restrict__ outF)
{
    const int gy = blockIdx.y;
    const int mod = gy >> 4, rem = gy & 15;
    const int e = rem >> 2, mt = rem & 3;
    const int grp = mod * 4 + e;
    const int cnt = counts_all[grp];
    const int row0 = mt * 256;
    if (row0 >= cnt) return;
    const int rbase = rowbase_all[grp];
    const int valid = min(256, cnt - row0);
    const int n0 = blockIdx.x * 128;
    const int* rows = rows_all + mod * 1024;

    __shared__ alignas(16) __bf16 As[256 * 64];
    __shared__ alignas(16) __bf16 Bs[128 * 64];

    const int tid = threadIdx.x;
    const int l = tid & 63, w = tid >> 6;
    const int wr = w >> 1, wc = w & 1;          // wr 0..3, wc 0..1

    // ---- A staging: 4 units/thread over flat 0..2047 (rows 0..255 x 8 chunks)
    const __bf16* aptr[4];
    int woffA[4];
    const __bf16* abase2 = GATHER ? Abase : (Abase + (size_t)mod * 1024 * (size_t)K);
    #pragma unroll
    for (int i = 0; i < 4; ++i) {
        int flat = tid + i * 512;
        int rr = flat >> 3, cc = flat & 7;
        int ri = rbase + row0 + min(rr, valid - 1);
        int ga = GATHER ? rows[ri] : ri;
        aptr[i] = abase2 + (size_t)ga * K + cc * 8;
        woffA[i] = rr * 64 + ((cc ^ (rr & 7)) * 8);
    }
    // ---- B staging: 2 units/thread over u 0..1023; unit = k-rows (2rp,2rp+1) x n-cols 4cq..+3
    const float* bp0 = Bsrc + (size_t)grp * K * N + n0;
    const float* bptr[2][2];
    int boff[2], bx[2];
    #pragma unroll
    for (int i = 0; i < 2; ++i) {
        int u = tid + i * 512;
        int rp = u >> 5, cq = u & 31;
        bptr[i][0] = bp0 + (size_t)(2 * rp) * N + 4 * cq;
        bptr[i][1] = bp0 + (size_t)(2 * rp + 1) * N + 4 * cq;
        boff[i] = (4 * cq) * 64 + ((rp & 3) << 1);
        bx[i] = (rp >> 2) ^ (4 * (cq & 1)) ^ ((cq >> 1) & 7);
    }

    f32x4 acc[4][4];
    f32x4 zero = {0.f, 0.f, 0.f, 0.f};
    #pragma unroll
    for (int mi = 0; mi < 4; ++mi)
        #pragma unroll
        for (int ni = 0; ni < 4; ++ni) acc[mi][ni] = zero;

    bf16x8 av[4], avn[4];
    f32x4 bv[2][2], bvn[2][2];
    #pragma unroll
    for (int i = 0; i < 4; ++i) av[i] = *(const bf16x8*)aptr[i];
    #pragma unroll
    for (int i = 0; i < 2; ++i) {
        bv[i][0] = *(const f32x4*)bptr[i][0];
        bv[i][1] = *(const f32x4*)bptr[i][1];
    }

    for (int k0 = 0; k0 < K; k0 += 64) {
        __syncthreads();
        #pragma unroll
        for (int i = 0; i < 4; ++i) *(bf16x8*)(As + woffA[i]) = av[i];
        #pragma unroll
        for (int i = 0; i < 2; ++i) {
            #pragma unroll
            for (int qq = 0; qq < 4; ++qq) {
                bf16x2 val = {(__bf16)bv[i][0][qq], (__bf16)bv[i][1][qq]};
                *(bf16x2*)(Bs + boff[i] + qq * 64 + ((bx[i] ^ qq) << 3)) = val;
            }
        }
        if (k0 + 64 < K) {
            #pragma unroll
            for (int i = 0; i < 4; ++i) {
                aptr[i] += 64;
                avn[i] = *(const bf16x8*)aptr[i];
            }
            #pragma unroll
            for (int i = 0; i < 2; ++i) {
                bptr[i][0] += (size_t)64 * N;
                bptr[i][1] += (size_t)64 * N;
                bvn[i][0] = *(const f32x4*)bptr[i][0];
                bvn[i][1] = *(const f32x4*)bptr[i][1];
            }
        }
        __syncthreads();
        #pragma unroll
        for (int kk = 0; kk < 2; ++kk) {
            bf16x8 af[4], bfv[4];
            #pragma unroll
            for (int mi = 0; mi < 4; ++mi) {
                int row = wr * 64 + mi * 16 + (l & 15);
                int cc = (kk * 4 + (l >> 4)) ^ (row & 7);
                af[mi] = *(const bf16x8*)(As + row * 64 + cc * 8);
            }
            #pragma unroll
            for (int ni = 0; ni < 4; ++ni) {
                int nrow = wc * 64 + ni * 16 + (l & 15);
                int gg = (nrow ^ (nrow >> 3)) & 7;
                int cc = (kk * 4 + (l >> 4)) ^ gg;
                bfv[ni] = *(const bf16x8*)(Bs + nrow * 64 + cc * 8);
            }
            #pragma unroll
            for (int mi = 0; mi < 4; ++mi)
                #pragma unroll
                for (int ni = 0; ni < 4; ++ni)
                    acc[mi][ni] = __builtin_amdgcn_mfma_f32_16x16x32_bf16(
                        af[mi], bfv[ni], acc[mi][ni], 0, 0, 0);
        }
        #pragma unroll
        for (int i = 0; i < 4; ++i) av[i] = avn[i];
        #pragma unroll
        for (int i = 0; i < 2; ++i) {
            bv[i][0] = bvn[i][0];
            bv[i][1] = bvn[i][1];
        }
    }

    const int lrow = l >> 4, lcol = l & 15;
    #pragma unroll
    for (int ni = 0; ni < 4; ++ni) {
        int col = n0 + wc * 64 + ni * 16 + lcol;
        float bval = bias[(size_t)grp * N + col];
        #pragma unroll
        for (int mi = 0; mi < 4; ++mi) {
            #pragma unroll
            for (int j = 0; j < 4; ++j) {
                int rt = wr * 64 + mi * 16 + lrow * 4 + j;
                if (rt < valid) {
                    float v = acc[mi][ni][j] + bval;
                    if (RELU) v = fmaxf(v, 0.f);
                    int crow = rbase + row0 + rt;
                    if (OUTBF) {
                        outB[((size_t)mod * 1024 + crow) * N + col] = (__bf16)v;
                    } else {
                        int tokid = rows[crow];
                        outF[((size_t)mod * 1024 + tokid) * N + col] = v;
                    }
                }
            }
        }
    }
}

// ---------------------------------------------------------------- poly + sigmoid
__global__ __launch_bounds__(256) void poly_kernel(
    const float* __restrict__ input, const float* __restrict__ moe,
    float* __restrict__ out)
{
    const int b = blockIdx.x, tid = threadIdx.x;
    float4 f0 = *(const float4*)(moe + (size_t)(0 * 1024 + b) * 1024 + tid * 4); // transform
    float4 f1 = *(const float4*)(moe + (size_t)(1 * 1024 + b) * 1024 + tid * 4); // add
    float4 f2 = *(const float4*)(moe + (size_t)(2 * 1024 + b) * 1024 + tid * 4); // quad
    float4 f3 = *(const float4*)(moe + (size_t)(3 * 1024 + b) * 1024 + tid * 4); // cubic
    float4 f4 = *(const float4*)(moe + (size_t)(4 * 1024 + b) * 1024 + tid * 4); // fourth
    const float4* ipv = (const float4*)(input + (size_t)b * 10240);
    float4* opv = (float4*)(out + (size_t)b * 10240);
    #pragma unroll
    for (int t = 0; t < 10; ++t) {
        float4 x = ipv[t * 256 + tid];
        float4 r;
        {
            float i2 = x.x * x.x;
            float p = i2 * (i2 * f4.x + x.x * f3.x + f2.x) + x.x * f0.x + f1.x;
            r.x = 1.f / (1.f + __expf(-p));
        }
        {
            float i2 = x.y * x.y;
            float p = i2 * (i2 * f4.y + x.y * f3.y + f2.y) + x.y * f0.y + f1.y;
            r.y = 1.f / (1.f + __expf(-p));
        }
        {
            float i2 = x.z * x.z;
            float p = i2 * (i2 * f4.z + x.z * f3.z + f2.z) + x.z * f0.z + f1.z;
            r.z = 1.f / (1.f + __expf(-p));
        }
        {
            float i2 = x.w * x.w;
            float p = i2 * (i2 * f4.w + x.w * f3.w + f2.w) + x.w * f0.w + f1.w;
            r.w = 1.f / (1.f + __expf(-p));
        }
        opv[t * 256 + tid] = r;
    }
}

// ---------------------------------------------------------------- loss
__global__ void loss_kernel(const int* __restrict__ counts, float* __restrict__ out_loss)
{
    if (threadIdx.x == 0 && blockIdx.x == 0) {
        float total = 0.f;
        for (int n = 0; n < NMOE; ++n) {
            const float m = 256.f;
            float var = 0.f;
            for (int e = 0; e < 4; ++e) {
                float d = (float)counts[n * 4 + e] - m;
                var += d * d;
            }
            var *= (1.f / 3.f);                       // ddof=1
            float cv2 = var / (m * m + 1e-10f);
            total += 2.f * cv2 * 1e-2f;               // importance == load == counts
        }
        *out_loss = total;
    }
}

// ---------------------------------------------------------------- launch
extern "C" void kernel_launch(void* const* d_in, const int* in_sizes, int n_in,
                              void* d_out, int out_size, void* d_ws, size_t ws_size,
                              hipStream_t stream)
{
    (void)in_sizes; (void)n_in; (void)out_size; (void)ws_size;
    const float* input = (const float*)d_in[0];
    const float* c1w   = (const float*)d_in[1];
    const float* c1b   = (const float*)d_in[2];
    const float* c2w   = (const float*)d_in[3];
    const float* c2b   = (const float*)d_in[4];
    const float* wgate = (const float*)d_in[5];
    const float* w1    = (const float*)d_in[6];
    const float* b1    = (const float*)d_in[7];
    const float* w2    = (const float*)d_in[8];
    const float* b2    = (const float*)d_in[9];
    float* out = (float*)d_out;

    char* ws = (char*)d_ws;
    float*  tok_f32   = (float*)(ws + 0);                 //  4 MB
    __bf16* tok_bf16  = (__bf16*)(ws + 4194304);          //  2 MB
    __bf16* h         = (__bf16*)(ws + 6291456);          // 20.97 MB [5][1024][2048] bf16
    float*  moe_out   = (float*)(ws + 27262976);          // 20.97 MB [5][1024][1024] f32
    int*    rows      = (int*)(ws + 48234496);            // [5][1024]
    int*    expert_id = (int*)(ws + 48254976);            // [5][1024]
    int*    counts    = (int*)(ws + 48275456);            // [5][4]
    int*    row_base  = (int*)(ws + 48275536);            // [5][4]

    hipMemsetAsync(counts, 0, NMOE * NEXP * sizeof(int), stream);

    conv_tok_kernel<<<1024, 256, 0, stream>>>(input, c1w, c1b, c2w, c2b, tok_f32, tok_bf16);
    gating_kernel<<<1280, 256, 0, stream>>>(tok_f32, wgate, expert_id, counts);
    scatter_kernel<<<5, 1024, 0, stream>>>(expert_id, counts, row_base, rows);

    moe_gemm_kernel<1024, 2048, true, true, true><<<dim3(16, 80), 512, 0, stream>>>(
        tok_bf16, w1, b1, rows, counts, row_base, h, nullptr);
    moe_gemm_kernel<2048, 1024, false, false, false><<<dim3(8, 80), 512, 0, stream>>>(
        h, w2, b2, rows, counts, row_base, nullptr, moe_out);

    poly_kernel<<<1024, 256, 0, stream>>>(input, moe_out, out);
    loss_kernel<<<1, 64, 0, stream>>>(counts, out + 10485760);
}

// Round 5
// 514.897 us; speedup vs baseline: 1.4297x; 1.1518x over previous
//
#include <hip/hip_runtime.h>
#include <hip/hip_bf16.h>

// ED_Fourth_MOE round 5:
//  - conv: round-1 LDS layout (stage planes ONCE, 51KB) + t-amortized conv1
//    (each plane's patch read once into regs, feeds acc[ts-1..ts+1]).
//    Per-accumulator FMA order and statement shapes are VERBATIM round-1
//    (dt ascending, dw ascending, dh-chain) -> bit-exact tok -> same argmax.
//  - GEMM: round-4 BM=256 fused-transpose kernel (proven).

typedef __bf16 bf16x8 __attribute__((ext_vector_type(8)));
typedef __bf16 bf16x4 __attribute__((ext_vector_type(4)));
typedef __bf16 bf16x2 __attribute__((ext_vector_type(2)));
typedef float f32x4 __attribute__((ext_vector_type(4)));

#define NMOE 5
#define NEXP 4

// ---------------------------------------------------------------- conv fused
__global__ __launch_bounds__(256) void conv_tok_kernel(
    const float* __restrict__ input, const float* __restrict__ c1w,
    const float* __restrict__ c1b, const float* __restrict__ c2w,
    const float* __restrict__ c2b, float* __restrict__ tok_f32,
    __bf16* __restrict__ tok_bf16)
{
    __shared__ float in_s[10][34][34];
    __shared__ float P[34][34];
    const int b = blockIdx.x, tid = threadIdx.x;

    float* ls = &in_s[0][0][0];
    for (int i = tid; i < 10 * 34 * 34; i += 256) ls[i] = 0.f;
    for (int i = tid; i < 34 * 34; i += 256) (&P[0][0])[i] = 0.f;
    __syncthreads();

    const float* ip = input + (size_t)b * 10240;
    for (int i = tid; i < 2560; i += 256) {
        int t = i >> 8, rem = i & 255;
        int h = rem >> 3, w4 = rem & 7;
        float4 v = ((const float4*)ip)[i];
        float* dst = &in_s[t][h + 1][w4 * 4 + 1];
        dst[0] = v.x; dst[1] = v.y; dst[2] = v.z; dst[3] = v.w;
    }
    __syncthreads();

    const int wcol = tid & 31;
    const int r0 = (tid >> 5) * 4;
    const float c2bias = c2b[0];
    float tk0 = c2bias, tk1 = c2bias, tk2 = c2bias, tk3 = c2bias;

    for (int c = 0; c < 10; ++c) {
        float w1l[27];
        #pragma unroll
        for (int i = 0; i < 27; ++i) w1l[i] = c1w[c * 27 + i];
        const float c1bias = c1b[c];

        // 10 live conv1 accumulators per pixel (fully unrolled indices only)
        float a0[10], a1[10], a2[10], a3[10];
        #pragma unroll
        for (int t = 0; t < 10; ++t) {
            a0[t] = c1bias; a1[t] = c1bias; a2[t] = c1bias; a3[t] = c1bias;
        }

        #pragma unroll
        for (int ts = 0; ts < 10; ++ts) {
            // ---- load 6x3 patch of plane ts into registers (read ONCE)
            float p0[3], p1[3], p2[3], p3[3], p4[3], p5[3];
            #pragma unroll
            for (int dw = 0; dw < 3; ++dw) {
                p0[dw] = in_s[ts][r0 + 0][wcol + dw];
                p1[dw] = in_s[ts][r0 + 1][wcol + dw];
                p2[dw] = in_s[ts][r0 + 2][wcol + dw];
                p3[dw] = in_s[ts][r0 + 3][wcol + dw];
                p4[dw] = in_s[ts][r0 + 4][wcol + dw];
                p5[dw] = in_s[ts][r0 + 5][wcol + dw];
            }
            // ---- plane ts feeds: dt=0 -> t=ts+1, dt=1 -> t=ts, dt=2 -> t=ts-1.
            // As ts ascends, each acc[t] receives dt=0,1,2 in ascending order ==
            // round-1's dt loop. Statements verbatim round-1.
            #pragma unroll
            for (int dt = 0; dt < 3; ++dt) {
                const int t = ts - dt + 1;
                if (t < 0 || t > 9) continue;
                #pragma unroll
                for (int dw = 0; dw < 3; ++dw) {
                    float u0 = w1l[dt * 9 + 0 + dw];
                    float u1 = w1l[dt * 9 + 3 + dw];
                    float u2 = w1l[dt * 9 + 6 + dw];
                    a0[t] += u0 * p0[dw] + u1 * p1[dw] + u2 * p2[dw];
                    a1[t] += u0 * p1[dw] + u1 * p2[dw] + u2 * p3[dw];
                    a2[t] += u0 * p2[dw] + u1 * p3[dw] + u2 * p4[dw];
                    a3[t] += u0 * p3[dw] + u1 * p4[dw] + u2 * p5[dw];
                }
            }
            // ---- acc[ts-1] is complete: P write + conv2 (round-1 verbatim)
            if (ts >= 1) {
                const int td = ts - 1;
                __syncthreads();   // previous plane's conv2 reads done
                P[r0 + 1][wcol + 1] = fmaxf(a0[td], 0.f);
                P[r0 + 2][wcol + 1] = fmaxf(a1[td], 0.f);
                P[r0 + 3][wcol + 1] = fmaxf(a2[td], 0.f);
                P[r0 + 4][wcol + 1] = fmaxf(a3[td], 0.f);
                __syncthreads();
                const int wb = (c * 10 + td) * 9;
                #pragma unroll
                for (int dw = 0; dw < 3; ++dw) {
                    float q0 = P[r0 + 0][wcol + dw];
                    float q1 = P[r0 + 1][wcol + dw];
                    float q2 = P[r0 + 2][wcol + dw];
                    float q3 = P[r0 + 3][wcol + dw];
                    float q4 = P[r0 + 4][wcol + dw];
                    float q5 = P[r0 + 5][wcol + dw];
                    float u0 = c2w[wb + 0 + dw];
                    float u1 = c2w[wb + 3 + dw];
                    float u2 = c2w[wb + 6 + dw];
                    tk0 += u0 * q0 + u1 * q1 + u2 * q2;
                    tk1 += u0 * q1 + u1 * q2 + u2 * q3;
                    tk2 += u0 * q2 + u1 * q3 + u2 * q4;
                    tk3 += u0 * q3 + u1 * q4 + u2 * q5;
                }
            }
        }
        // ---- tail: td = 9
        {
            __syncthreads();
            P[r0 + 1][wcol + 1] = fmaxf(a0[9], 0.f);
            P[r0 + 2][wcol + 1] = fmaxf(a1[9], 0.f);
            P[r0 + 3][wcol + 1] = fmaxf(a2[9], 0.f);
            P[r0 + 4][wcol + 1] = fmaxf(a3[9], 0.f);
            __syncthreads();
            const int wb = (c * 10 + 9) * 9;
            #pragma unroll
            for (int dw = 0; dw < 3; ++dw) {
                float q0 = P[r0 + 0][wcol + dw];
                float q1 = P[r0 + 1][wcol + dw];
                float q2 = P[r0 + 2][wcol + dw];
                float q3 = P[r0 + 3][wcol + dw];
                float q4 = P[r0 + 4][wcol + dw];
                float q5 = P[r0 + 5][wcol + dw];
                float u0 = c2w[wb + 0 + dw];
                float u1 = c2w[wb + 3 + dw];
                float u2 = c2w[wb + 6 + dw];
                tk0 += u0 * q0 + u1 * q1 + u2 * q2;
                tk1 += u0 * q1 + u1 * q2 + u2 * q3;
                tk2 += u0 * q2 + u1 * q3 + u2 * q4;
                tk3 += u0 * q3 + u1 * q4 + u2 * q5;
            }
        }
    }
    float o0 = fmaxf(tk0, 0.f), o1 = fmaxf(tk1, 0.f);
    float o2 = fmaxf(tk2, 0.f), o3 = fmaxf(tk3, 0.f);
    size_t base = (size_t)b * 1024 + (size_t)r0 * 32 + wcol;
    tok_f32[base] = o0; tok_f32[base + 32] = o1;
    tok_f32[base + 64] = o2; tok_f32[base + 96] = o3;
    tok_bf16[base] = (__bf16)o0; tok_bf16[base + 32] = (__bf16)o1;
    tok_bf16[base + 64] = (__bf16)o2; tok_bf16[base + 96] = (__bf16)o3;
}

// ---------------------------------------------------------------- gating
__global__ __launch_bounds__(256) void gating_kernel(
    const float* __restrict__ tok, const float* __restrict__ w_gate,
    int* __restrict__ expert_id, int* __restrict__ counts)
{
    int gw = blockIdx.x * 4 + (threadIdx.x >> 6);
    int l = threadIdx.x & 63;
    int n = gw >> 10, b = gw & 1023;
    const float* trow = tok + (size_t)b * 1024;
    const float* wg = w_gate + (size_t)n * 4096;
    float a0 = 0.f, a1 = 0.f, a2 = 0.f, a3 = 0.f;
    #pragma unroll
    for (int i = 0; i < 16; ++i) {
        int d = i * 64 + l;
        float tv = trow[d];
        float4 g4 = *(const float4*)(wg + d * 4);
        a0 += tv * g4.x; a1 += tv * g4.y; a2 += tv * g4.z; a3 += tv * g4.w;
    }
    #pragma unroll
    for (int off = 32; off >= 1; off >>= 1) {
        a0 += __shfl_xor(a0, off);
        a1 += __shfl_xor(a1, off);
        a2 += __shfl_xor(a2, off);
        a3 += __shfl_xor(a3, off);
    }
    if (l == 0) {
        int e = 0; float best = a0;
        if (a1 > best) { best = a1; e = 1; }
        if (a2 > best) { best = a2; e = 2; }
        if (a3 > best) { best = a3; e = 3; }
        expert_id[n * 1024 + b] = e;
        atomicAdd(&counts[n * 4 + e], 1);
    }
}

// ---------------------------------------------------------------- scatter
__global__ __launch_bounds__(1024) void scatter_kernel(
    const int* __restrict__ expert_id, const int* __restrict__ counts,
    int* __restrict__ row_base, int* __restrict__ rows)
{
    __shared__ int cur[4];
    int n = blockIdx.x, tid = threadIdx.x;
    if (tid == 0) {
        int c0 = counts[n * 4 + 0], c1 = counts[n * 4 + 1], c2 = counts[n * 4 + 2];
        cur[0] = 0; cur[1] = c0; cur[2] = c0 + c1; cur[3] = c0 + c1 + c2;
        row_base[n * 4 + 0] = cur[0]; row_base[n * 4 + 1] = cur[1];
        row_base[n * 4 + 2] = cur[2]; row_base[n * 4 + 3] = cur[3];
    }
    __syncthreads();
    int e = expert_id[n * 1024 + tid];
    int pos = atomicAdd(&cur[e], 1);
    rows[n * 1024 + pos] = tid;
}

// ---------------------------------------------------------------- grouped GEMM (BM=256)
// grid y = mod*16 + e*4 + mt (80). C tile 256x128, BK=64, 8 waves (4m x 2n), wave 64x64.
// A: bf16 k-contiguous (gathered for GEMM1). B: fp32 [grp][K][N] transposed+converted
// to bf16 in LDS staging. Swizzles verbatim from proven round-3 kernel.
template <int K, int N, bool GATHER, bool RELU, bool OUTBF>
__global__ __launch_bounds__(512) void moe_gemm_kernel(
    const __bf16* __restrict__ Abase, const float* __restrict__ Bsrc,
    const float* __restrict__ bias, const int* __restrict__ rows_all,
    const int* __restrict__ counts_all, const int* __restrict__ rowbase_all,
    __bf16* __restrict__ outB, float* __restrict__ outF)
{
    const int gy = blockIdx.y;
    const int mod = gy >> 4, rem = gy & 15;
    const int e = rem >> 2, mt = rem & 3;
    const int grp = mod * 4 + e;
    const int cnt = counts_all[grp];
    const int row0 = mt * 256;
    if (row0 >= cnt) return;
    const int rbase = rowbase_all[grp];
    const int valid = min(256, cnt - row0);
    const int n0 = blockIdx.x * 128;
    const int* rows = rows_all + mod * 1024;

    __shared__ alignas(16) __bf16 As[256 * 64];
    __shared__ alignas(16) __bf16 Bs[128 * 64];

    const int tid = threadIdx.x;
    const int l = tid & 63, w = tid >> 6;
    const int wr = w >> 1, wc = w & 1;          // wr 0..3, wc 0..1

    // ---- A staging: 4 units/thread over flat 0..2047 (rows 0..255 x 8 chunks)
    const __bf16* aptr[4];
    int woffA[4];
    const __bf16* abase2 = GATHER ? Abase : (Abase + (size_t)mod * 1024 * (size_t)K);
    #pragma unroll
    for (int i = 0; i < 4; ++i) {
        int flat = tid + i * 512;
        int rr = flat >> 3, cc = flat & 7;
        int ri = rbase + row0 + min(rr, valid - 1);
        int ga = GATHER ? rows[ri] : ri;
        aptr[i] = abase2 + (size_t)ga * K + cc * 8;
        woffA[i] = rr * 64 + ((cc ^ (rr & 7)) * 8);
    }
    // ---- B staging: 2 units/thread over u 0..1023; unit = k-rows (2rp,2rp+1) x n-cols 4cq..+3
    const float* bp0 = Bsrc + (size_t)grp * K * N + n0;
    const float* bptr[2][2];
    int boff[2], bx[2];
    #pragma unroll
    for (int i = 0; i < 2; ++i) {
        int u = tid + i * 512;
        int rp = u >> 5, cq = u & 31;
        bptr[i][0] = bp0 + (size_t)(2 * rp) * N + 4 * cq;
        bptr[i][1] = bp0 + (size_t)(2 * rp + 1) * N + 4 * cq;
        boff[i] = (4 * cq) * 64 + ((rp & 3) << 1);
        bx[i] = (rp >> 2) ^ (4 * (cq & 1)) ^ ((cq >> 1) & 7);
    }

    f32x4 acc[4][4];
    f32x4 zero = {0.f, 0.f, 0.f, 0.f};
    #pragma unroll
    for (int mi = 0; mi < 4; ++mi)
        #pragma unroll
        for (int ni = 0; ni < 4; ++ni) acc[mi][ni] = zero;

    bf16x8 av[4], avn[4];
    f32x4 bv[2][2], bvn[2][2];
    #pragma unroll
    for (int i = 0; i < 4; ++i) av[i] = *(const bf16x8*)aptr[i];
    #pragma unroll
    for (int i = 0; i < 2; ++i) {
        bv[i][0] = *(const f32x4*)bptr[i][0];
        bv[i][1] = *(const f32x4*)bptr[i][1];
    }

    for (int k0 = 0; k0 < K; k0 += 64) {
        __syncthreads();
        #pragma unroll
        for (int i = 0; i < 4; ++i) *(bf16x8*)(As + woffA[i]) = av[i];
        #pragma unroll
        for (int i = 0; i < 2; ++i) {
            #pragma unroll
            for (int qq = 0; qq < 4; ++qq) {
                bf16x2 val = {(__bf16)bv[i][0][qq], (__bf16)bv[i][1][qq]};
                *(bf16x2*)(Bs + boff[i] + qq * 64 + ((bx[i] ^ qq) << 3)) = val;
            }
        }
        if (k0 + 64 < K) {
            #pragma unroll
            for (int i = 0; i < 4; ++i) {
                aptr[i] += 64;
                avn[i] = *(const bf16x8*)aptr[i];
            }
            #pragma unroll
            for (int i = 0; i < 2; ++i) {
                bptr[i][0] += (size_t)64 * N;
                bptr[i][1] += (size_t)64 * N;
                bvn[i][0] = *(const f32x4*)bptr[i][0];
                bvn[i][1] = *(const f32x4*)bptr[i][1];
            }
        }
        __syncthreads();
        #pragma unroll
        for (int kk = 0; kk < 2; ++kk) {
            bf16x8 af[4], bfv[4];
            #pragma unroll
            for (int mi = 0; mi < 4; ++mi) {
                int row = wr * 64 + mi * 16 + (l & 15);
                int cc = (kk * 4 + (l >> 4)) ^ (row & 7);
                af[mi] = *(const bf16x8*)(As + row * 64 + cc * 8);
            }
            #pragma unroll
            for (int ni = 0; ni < 4; ++ni) {
                int nrow = wc * 64 + ni * 16 + (l & 15);
                int gg = (nrow ^ (nrow >> 3)) & 7;
                int cc = (kk * 4 + (l >> 4)) ^ gg;
                bfv[ni] = *(const bf16x8*)(Bs + nrow * 64 + cc * 8);
            }
            #pragma unroll
            for (int mi = 0; mi < 4; ++mi)
                #pragma unroll
                for (int ni = 0; ni < 4; ++ni)
                    acc[mi][ni] = __builtin_amdgcn_mfma_f32_16x16x32_bf16(
                        af[mi], bfv[ni], acc[mi][ni], 0, 0, 0);
        }
        #pragma unroll
        for (int i = 0; i < 4; ++i) av[i] = avn[i];
        #pragma unroll
        for (int i = 0; i < 2; ++i) {
            bv[i][0] = bvn[i][0];
            bv[i][1] = bvn[i][1];
        }
    }

    const int lrow = l >> 4, lcol = l & 15;
    #pragma unroll
    for (int ni = 0; ni < 4; ++ni) {
        int col = n0 + wc * 64 + ni * 16 + lcol;
        float bval = bias[(size_t)grp * N + col];
        #pragma unroll
        for (int mi = 0; mi < 4; ++mi) {
            #pragma unroll
            for (int j = 0; j < 4; ++j) {
                int rt = wr * 64 + mi * 16 + lrow * 4 + j;
                if (rt < valid) {
                    float v = acc[mi][ni][j] + bval;
                    if (RELU) v = fmaxf(v, 0.f);
                    int crow = rbase + row0 + rt;
                    if (OUTBF) {
                        outB[((size_t)mod * 1024 + crow) * N + col] = (__bf16)v;
                    } else {
                        int tokid = rows[crow];
                        outF[((size_t)mod * 1024 + tokid) * N + col] = v;
                    }
                }
            }
        }
    }
}

// ---------------------------------------------------------------- poly + sigmoid
__global__ __launch_bounds__(256) void poly_kernel(
    const float* __restrict__ input, const float* __restrict__ moe,
    float* __restrict__ out)
{
    const int b = blockIdx.x, tid = threadIdx.x;
    float4 f0 = *(const float4*)(moe + (size_t)(0 * 1024 + b) * 1024 + tid * 4); // transform
    float4 f1 = *(const float4*)(moe + (size_t)(1 * 1024 + b) * 1024 + tid * 4); // add
    float4 f2 = *(const float4*)(moe + (size_t)(2 * 1024 + b) * 1024 + tid * 4); // quad
    float4 f3 = *(const float4*)(moe + (size_t)(3 * 1024 + b) * 1024 + tid * 4); // cubic
    float4 f4 = *(const float4*)(moe + (size_t)(4 * 1024 + b) * 1024 + tid * 4); // fourth
    const float4* ipv = (const float4*)(input + (size_t)b * 10240);
    float4* opv = (float4*)(out + (size_t)b * 10240);
    #pragma unroll
    for (int t = 0; t < 10; ++t) {
        float4 x = ipv[t * 256 + tid];
        float4 r;
        {
            float i2 = x.x * x.x;
            float p = i2 * (i2 * f4.x + x.x * f3.x + f2.x) + x.x * f0.x + f1.x;
            r.x = 1.f / (1.f + __expf(-p));
        }
        {
            float i2 = x.y * x.y;
            float p = i2 * (i2 * f4.y + x.y * f3.y + f2.y) + x.y * f0.y + f1.y;
            r.y = 1.f / (1.f + __expf(-p));
        }
        {
            float i2 = x.z * x.z;
            float p = i2 * (i2 * f4.z + x.z * f3.z + f2.z) + x.z * f0.z + f1.z;
            r.z = 1.f / (1.f + __expf(-p));
        }
        {
            float i2 = x.w * x.w;
            float p = i2 * (i2 * f4.w + x.w * f3.w + f2.w) + x.w * f0.w + f1.w;
            r.w = 1.f / (1.f + __expf(-p));
        }
        opv[t * 256 + tid] = r;
    }
}

// ---------------------------------------------------------------- loss
__global__ void loss_kernel(const int* __restrict__ counts, float* __restrict__ out_loss)
{
    if (threadIdx.x == 0 && blockIdx.x == 0) {
        float total = 0.f;
        for (int n = 0; n < NMOE; ++n) {
            const float m = 256.f;
            float var = 0.f;
            for (int e = 0; e < 4; ++e) {
                float d = (float)counts[n * 4 + e] - m;
                var += d * d;
            }
            var *= (1.f / 3.f);                       // ddof=1
            float cv2 = var / (m * m + 1e-10f);
            total += 2.f * cv2 * 1e-2f;               // importance == load == counts
        }
        *out_loss = total;
    }
}

// ---------------------------------------------------------------- launch
extern "C" void kernel_launch(void* const* d_in, const int* in_sizes, int n_in,
                              void* d_out, int out_size, void* d_ws, size_t ws_size,
                              hipStream_t stream)
{
    (void)in_sizes; (void)n_in; (void)out_size; (void)ws_size;
    const float* input = (const float*)d_in[0];
    const float* c1w   = (const float*)d_in[1];
    const float* c1b   = (const float*)d_in[2];
    const float* c2w   = (const float*)d_in[3];
    const float* c2b   = (const float*)d_in[4];
    const float* wgate = (const float*)d_in[5];
    const float* w1    = (const float*)d_in[6];
    const float* b1    = (const float*)d_in[7];
    const float* w2    = (const float*)d_in[8];
    const float* b2    = (const float*)d_in[9];
    float* out = (float*)d_out;

    char* ws = (char*)d_ws;
    float*  tok_f32   = (float*)(ws + 0);                 //  4 MB
    __bf16* tok_bf16  = (__bf16*)(ws + 4194304);          //  2 MB
    __bf16* h         = (__bf16*)(ws + 6291456);          // 20.97 MB [5][1024][2048] bf16
    float*  moe_out   = (float*)(ws + 27262976);          // 20.97 MB [5][1024][1024] f32
    int*    rows      = (int*)(ws + 48234496);            // [5][1024]
    int*    expert_id = (int*)(ws + 48254976);            // [5][1024]
    int*    counts    = (int*)(ws + 48275456);            // [5][4]
    int*    row_base  = (int*)(ws + 48275536);            // [5][4]

    hipMemsetAsync(counts, 0, NMOE * NEXP * sizeof(int), stream);

    conv_tok_kernel<<<1024, 256, 0, stream>>>(input, c1w, c1b, c2w, c2b, tok_f32, tok_bf16);
    gating_kernel<<<1280, 256, 0, stream>>>(tok_f32, wgate, expert_id, counts);
    scatter_kernel<<<5, 1024, 0, stream>>>(expert_id, counts, row_base, rows);

    moe_gemm_kernel<1024, 2048, true, true, true><<<dim3(16, 80), 512, 0, stream>>>(
        tok_bf16, w1, b1, rows, counts, row_base, h, nullptr);
    moe_gemm_kernel<2048, 1024, false, false, false><<<dim3(8, 80), 512, 0, stream>>>(
        h, w2, b2, rows, counts, row_base, nullptr, moe_out);

    poly_kernel<<<1024, 256, 0, stream>>>(input, moe_out, out);
    loss_kernel<<<1, 64, 0, stream>>>(counts, out + 10485760);
}

// Round 6
// 445.920 us; speedup vs baseline: 1.6508x; 1.1547x over previous
//
#include <hip/hip_runtime.h>
#include <hip/hip_bf16.h>

// ED_Fourth_MOE round 6:
//  - conv: identical code to round-5 (bit-exact tok) + __launch_bounds__(256,3):
//    LDS caps occupancy at 3 blocks/CU anyway, so allow ~170 VGPR and stop the
//    spilling that the default 8-wave-targeting regalloc causes (VGPR=68 observed
//    for a ~90-reg live set).
//  - GEMM: BN templated; GEMM2 uses BN=64 -> 320 blocks (was 160, 0.6 blocks/CU).
//    Swizzle algebra verified to generalize; per-output MFMA k-chain unchanged.

typedef __bf16 bf16x8 __attribute__((ext_vector_type(8)));
typedef __bf16 bf16x4 __attribute__((ext_vector_type(4)));
typedef __bf16 bf16x2 __attribute__((ext_vector_type(2)));
typedef float f32x4 __attribute__((ext_vector_type(4)));

#define NMOE 5
#define NEXP 4

// ---------------------------------------------------------------- conv fused
__global__ __launch_bounds__(256, 3) void conv_tok_kernel(
    const float* __restrict__ input, const float* __restrict__ c1w,
    const float* __restrict__ c1b, const float* __restrict__ c2w,
    const float* __restrict__ c2b, float* __restrict__ tok_f32,
    __bf16* __restrict__ tok_bf16)
{
    __shared__ float in_s[10][34][34];
    __shared__ float P[34][34];
    const int b = blockIdx.x, tid = threadIdx.x;

    float* ls = &in_s[0][0][0];
    for (int i = tid; i < 10 * 34 * 34; i += 256) ls[i] = 0.f;
    for (int i = tid; i < 34 * 34; i += 256) (&P[0][0])[i] = 0.f;
    __syncthreads();

    const float* ip = input + (size_t)b * 10240;
    for (int i = tid; i < 2560; i += 256) {
        int t = i >> 8, rem = i & 255;
        int h = rem >> 3, w4 = rem & 7;
        float4 v = ((const float4*)ip)[i];
        float* dst = &in_s[t][h + 1][w4 * 4 + 1];
        dst[0] = v.x; dst[1] = v.y; dst[2] = v.z; dst[3] = v.w;
    }
    __syncthreads();

    const int wcol = tid & 31;
    const int r0 = (tid >> 5) * 4;
    const float c2bias = c2b[0];
    float tk0 = c2bias, tk1 = c2bias, tk2 = c2bias, tk3 = c2bias;

    for (int c = 0; c < 10; ++c) {
        float w1l[27];
        #pragma unroll
        for (int i = 0; i < 27; ++i) w1l[i] = c1w[c * 27 + i];
        const float c1bias = c1b[c];

        // 10 live conv1 accumulators per pixel (fully unrolled indices only)
        float a0[10], a1[10], a2[10], a3[10];
        #pragma unroll
        for (int t = 0; t < 10; ++t) {
            a0[t] = c1bias; a1[t] = c1bias; a2[t] = c1bias; a3[t] = c1bias;
        }

        #pragma unroll
        for (int ts = 0; ts < 10; ++ts) {
            // ---- load 6x3 patch of plane ts into registers (read ONCE)
            float p0[3], p1[3], p2[3], p3[3], p4[3], p5[3];
            #pragma unroll
            for (int dw = 0; dw < 3; ++dw) {
                p0[dw] = in_s[ts][r0 + 0][wcol + dw];
                p1[dw] = in_s[ts][r0 + 1][wcol + dw];
                p2[dw] = in_s[ts][r0 + 2][wcol + dw];
                p3[dw] = in_s[ts][r0 + 3][wcol + dw];
                p4[dw] = in_s[ts][r0 + 4][wcol + dw];
                p5[dw] = in_s[ts][r0 + 5][wcol + dw];
            }
            // ---- plane ts feeds: dt=0 -> t=ts+1, dt=1 -> t=ts, dt=2 -> t=ts-1.
            #pragma unroll
            for (int dt = 0; dt < 3; ++dt) {
                const int t = ts - dt + 1;
                if (t < 0 || t > 9) continue;
                #pragma unroll
                for (int dw = 0; dw < 3; ++dw) {
                    float u0 = w1l[dt * 9 + 0 + dw];
                    float u1 = w1l[dt * 9 + 3 + dw];
                    float u2 = w1l[dt * 9 + 6 + dw];
                    a0[t] += u0 * p0[dw] + u1 * p1[dw] + u2 * p2[dw];
                    a1[t] += u0 * p1[dw] + u1 * p2[dw] + u2 * p3[dw];
                    a2[t] += u0 * p2[dw] + u1 * p3[dw] + u2 * p4[dw];
                    a3[t] += u0 * p3[dw] + u1 * p4[dw] + u2 * p5[dw];
                }
            }
            // ---- acc[ts-1] is complete: P write + conv2 (round-1 verbatim)
            if (ts >= 1) {
                const int td = ts - 1;
                __syncthreads();   // previous plane's conv2 reads done
                P[r0 + 1][wcol + 1] = fmaxf(a0[td], 0.f);
                P[r0 + 2][wcol + 1] = fmaxf(a1[td], 0.f);
                P[r0 + 3][wcol + 1] = fmaxf(a2[td], 0.f);
                P[r0 + 4][wcol + 1] = fmaxf(a3[td], 0.f);
                __syncthreads();
                const int wb = (c * 10 + td) * 9;
                #pragma unroll
                for (int dw = 0; dw < 3; ++dw) {
                    float q0 = P[r0 + 0][wcol + dw];
                    float q1 = P[r0 + 1][wcol + dw];
                    float q2 = P[r0 + 2][wcol + dw];
                    float q3 = P[r0 + 3][wcol + dw];
                    float q4 = P[r0 + 4][wcol + dw];
                    float q5 = P[r0 + 5][wcol + dw];
                    float u0 = c2w[wb + 0 + dw];
                    float u1 = c2w[wb + 3 + dw];
                    float u2 = c2w[wb + 6 + dw];
                    tk0 += u0 * q0 + u1 * q1 + u2 * q2;
                    tk1 += u0 * q1 + u1 * q2 + u2 * q3;
                    tk2 += u0 * q2 + u1 * q3 + u2 * q4;
                    tk3 += u0 * q3 + u1 * q4 + u2 * q5;
                }
            }
        }
        // ---- tail: td = 9
        {
            __syncthreads();
            P[r0 + 1][wcol + 1] = fmaxf(a0[9], 0.f);
            P[r0 + 2][wcol + 1] = fmaxf(a1[9], 0.f);
            P[r0 + 3][wcol + 1] = fmaxf(a2[9], 0.f);
            P[r0 + 4][wcol + 1] = fmaxf(a3[9], 0.f);
            __syncthreads();
            const int wb = (c * 10 + 9) * 9;
            #pragma unroll
            for (int dw = 0; dw < 3; ++dw) {
                float q0 = P[r0 + 0][wcol + dw];
                float q1 = P[r0 + 1][wcol + dw];
                float q2 = P[r0 + 2][wcol + dw];
                float q3 = P[r0 + 3][wcol + dw];
                float q4 = P[r0 + 4][wcol + dw];
                float q5 = P[r0 + 5][wcol + dw];
                float u0 = c2w[wb + 0 + dw];
                float u1 = c2w[wb + 3 + dw];
                float u2 = c2w[wb + 6 + dw];
                tk0 += u0 * q0 + u1 * q1 + u2 * q2;
                tk1 += u0 * q1 + u1 * q2 + u2 * q3;
                tk2 += u0 * q2 + u1 * q3 + u2 * q4;
                tk3 += u0 * q3 + u1 * q4 + u2 * q5;
            }
        }
    }
    float o0 = fmaxf(tk0, 0.f), o1 = fmaxf(tk1, 0.f);
    float o2 = fmaxf(tk2, 0.f), o3 = fmaxf(tk3, 0.f);
    size_t base = (size_t)b * 1024 + (size_t)r0 * 32 + wcol;
    tok_f32[base] = o0; tok_f32[base + 32] = o1;
    tok_f32[base + 64] = o2; tok_f32[base + 96] = o3;
    tok_bf16[base] = (__bf16)o0; tok_bf16[base + 32] = (__bf16)o1;
    tok_bf16[base + 64] = (__bf16)o2; tok_bf16[base + 96] = (__bf16)o3;
}

// ---------------------------------------------------------------- gating
__global__ __launch_bounds__(256) void gating_kernel(
    const float* __restrict__ tok, const float* __restrict__ w_gate,
    int* __restrict__ expert_id, int* __restrict__ counts)
{
    int gw = blockIdx.x * 4 + (threadIdx.x >> 6);
    int l = threadIdx.x & 63;
    int n = gw >> 10, b = gw & 1023;
    const float* trow = tok + (size_t)b * 1024;
    const float* wg = w_gate + (size_t)n * 4096;
    float a0 = 0.f, a1 = 0.f, a2 = 0.f, a3 = 0.f;
    #pragma unroll
    for (int i = 0; i < 16; ++i) {
        int d = i * 64 + l;
        float tv = trow[d];
        float4 g4 = *(const float4*)(wg + d * 4);
        a0 += tv * g4.x; a1 += tv * g4.y; a2 += tv * g4.z; a3 += tv * g4.w;
    }
    #pragma unroll
    for (int off = 32; off >= 1; off >>= 1) {
        a0 += __shfl_xor(a0, off);
        a1 += __shfl_xor(a1, off);
        a2 += __shfl_xor(a2, off);
        a3 += __shfl_xor(a3, off);
    }
    if (l == 0) {
        int e = 0; float best = a0;
        if (a1 > best) { best = a1; e = 1; }
        if (a2 > best) { best = a2; e = 2; }
        if (a3 > best) { best = a3; e = 3; }
        expert_id[n * 1024 + b] = e;
        atomicAdd(&counts[n * 4 + e], 1);
    }
}

// ---------------------------------------------------------------- scatter
__global__ __launch_bounds__(1024) void scatter_kernel(
    const int* __restrict__ expert_id, const int* __restrict__ counts,
    int* __restrict__ row_base, int* __restrict__ rows)
{
    __shared__ int cur[4];
    int n = blockIdx.x, tid = threadIdx.x;
    if (tid == 0) {
        int c0 = counts[n * 4 + 0], c1 = counts[n * 4 + 1], c2 = counts[n * 4 + 2];
        cur[0] = 0; cur[1] = c0; cur[2] = c0 + c1; cur[3] = c0 + c1 + c2;
        row_base[n * 4 + 0] = cur[0]; row_base[n * 4 + 1] = cur[1];
        row_base[n * 4 + 2] = cur[2]; row_base[n * 4 + 3] = cur[3];
    }
    __syncthreads();
    int e = expert_id[n * 1024 + tid];
    int pos = atomicAdd(&cur[e], 1);
    rows[n * 1024 + pos] = tid;
}

// ---------------------------------------------------------------- grouped GEMM (BM=256, BN templated)
// grid y = mod*16 + e*4 + mt (80). C tile 256xBN, BK=64, 8 waves (4m x 2n), wave 64x(BN/2).
// B: fp32 [grp][K][N] transposed+converted to bf16 in LDS staging.
// Swizzle: stored chunk = (k>>3) ^ g(n), g(n)=(n^(n>>3))&7 — valid for any BN (algebra
// holds with cq = u % (BN/4); reader uses the same g(n)).
template <int K, int N, int BN, bool GATHER, bool RELU, bool OUTBF>
__global__ __launch_bounds__(512) void moe_gemm_kernel(
    const __bf16* __restrict__ Abase, const float* __restrict__ Bsrc,
    const float* __restrict__ bias, const int* __restrict__ rows_all,
    const int* __restrict__ counts_all, const int* __restrict__ rowbase_all,
    __bf16* __restrict__ outB, float* __restrict__ outF)
{
    constexpr int CQ  = BN / 4;   // col-quads per k-row-pair group
    constexpr int UB  = BN / 64;  // B staging units per thread (2 for BN=128, 1 for 64)
    constexpr int NFR = BN / 32;  // n-fragments per wave

    const int gy = blockIdx.y;
    const int mod = gy >> 4, rem = gy & 15;
    const int e = rem >> 2, mt = rem & 3;
    const int grp = mod * 4 + e;
    const int cnt = counts_all[grp];
    const int row0 = mt * 256;
    if (row0 >= cnt) return;
    const int rbase = rowbase_all[grp];
    const int valid = min(256, cnt - row0);
    const int n0 = blockIdx.x * BN;
    const int* rows = rows_all + mod * 1024;

    __shared__ alignas(16) __bf16 As[256 * 64];
    __shared__ alignas(16) __bf16 Bs[BN * 64];

    const int tid = threadIdx.x;
    const int l = tid & 63, w = tid >> 6;
    const int wr = w >> 1, wc = w & 1;          // wr 0..3, wc 0..1

    // ---- A staging: 4 units/thread over flat 0..2047 (rows 0..255 x 8 chunks)
    const __bf16* aptr[4];
    int woffA[4];
    const __bf16* abase2 = GATHER ? Abase : (Abase + (size_t)mod * 1024 * (size_t)K);
    #pragma unroll
    for (int i = 0; i < 4; ++i) {
        int flat = tid + i * 512;
        int rr = flat >> 3, cc = flat & 7;
        int ri = rbase + row0 + min(rr, valid - 1);
        int ga = GATHER ? rows[ri] : ri;
        aptr[i] = abase2 + (size_t)ga * K + cc * 8;
        woffA[i] = rr * 64 + ((cc ^ (rr & 7)) * 8);
    }
    // ---- B staging: UB units/thread; unit = k-rows (2rp,2rp+1) x n-cols 4cq..+3
    const float* bp0 = Bsrc + (size_t)grp * K * N + n0;
    const float* bptr[UB][2];
    int boff[UB], bx[UB];
    #pragma unroll
    for (int i = 0; i < UB; ++i) {
        int u = tid + i * 512;
        int rp = u / CQ, cq = u % CQ;
        bptr[i][0] = bp0 + (size_t)(2 * rp) * N + 4 * cq;
        bptr[i][1] = bp0 + (size_t)(2 * rp + 1) * N + 4 * cq;
        boff[i] = (4 * cq) * 64 + ((rp & 3) << 1);
        bx[i] = (rp >> 2) ^ (4 * (cq & 1)) ^ ((cq >> 1) & 7);
    }

    f32x4 acc[4][NFR];
    f32x4 zero = {0.f, 0.f, 0.f, 0.f};
    #pragma unroll
    for (int mi = 0; mi < 4; ++mi)
        #pragma unroll
        for (int ni = 0; ni < NFR; ++ni) acc[mi][ni] = zero;

    bf16x8 av[4], avn[4];
    f32x4 bv[UB][2], bvn[UB][2];
    #pragma unroll
    for (int i = 0; i < 4; ++i) av[i] = *(const bf16x8*)aptr[i];
    #pragma unroll
    for (int i = 0; i < UB; ++i) {
        bv[i][0] = *(const f32x4*)bptr[i][0];
        bv[i][1] = *(const f32x4*)bptr[i][1];
    }

    for (int k0 = 0; k0 < K; k0 += 64) {
        __syncthreads();
        #pragma unroll
        for (int i = 0; i < 4; ++i) *(bf16x8*)(As + woffA[i]) = av[i];
        #pragma unroll
        for (int i = 0; i < UB; ++i) {
            #pragma unroll
            for (int qq = 0; qq < 4; ++qq) {
                bf16x2 val = {(__bf16)bv[i][0][qq], (__bf16)bv[i][1][qq]};
                *(bf16x2*)(Bs + boff[i] + qq * 64 + ((bx[i] ^ qq) << 3)) = val;
            }
        }
        if (k0 + 64 < K) {
            #pragma unroll
            for (int i = 0; i < 4; ++i) {
                aptr[i] += 64;
                avn[i] = *(const bf16x8*)aptr[i];
            }
            #pragma unroll
            for (int i = 0; i < UB; ++i) {
                bptr[i][0] += (size_t)64 * N;
                bptr[i][1] += (size_t)64 * N;
                bvn[i][0] = *(const f32x4*)bptr[i][0];
                bvn[i][1] = *(const f32x4*)bptr[i][1];
            }
        }
        __syncthreads();
        #pragma unroll
        for (int kk = 0; kk < 2; ++kk) {
            bf16x8 af[4], bfv[NFR];
            #pragma unroll
            for (int mi = 0; mi < 4; ++mi) {
                int row = wr * 64 + mi * 16 + (l & 15);
                int cc = (kk * 4 + (l >> 4)) ^ (row & 7);
                af[mi] = *(const bf16x8*)(As + row * 64 + cc * 8);
            }
            #pragma unroll
            for (int ni = 0; ni < NFR; ++ni) {
                int nrow = wc * (BN / 2) + ni * 16 + (l & 15);
                int gg = (nrow ^ (nrow >> 3)) & 7;
                int cc = (kk * 4 + (l >> 4)) ^ gg;
                bfv[ni] = *(const bf16x8*)(Bs + nrow * 64 + cc * 8);
            }
            #pragma unroll
            for (int mi = 0; mi < 4; ++mi)
                #pragma unroll
                for (int ni = 0; ni < NFR; ++ni)
                    acc[mi][ni] = __builtin_amdgcn_mfma_f32_16x16x32_bf16(
                        af[mi], bfv[ni], acc[mi][ni], 0, 0, 0);
        }
        #pragma unroll
        for (int i = 0; i < 4; ++i) av[i] = avn[i];
        #pragma unroll
        for (int i = 0; i < UB; ++i) {
            bv[i][0] = bvn[i][0];
            bv[i][1] = bvn[i][1];
        }
    }

    const int lrow = l >> 4, lcol = l & 15;
    #pragma unroll
    for (int ni = 0; ni < NFR; ++ni) {
        int col = n0 + wc * (BN / 2) + ni * 16 + lcol;
        float bval = bias[(size_t)grp * N + col];
        #pragma unroll
        for (int mi = 0; mi < 4; ++mi) {
            #pragma unroll
            for (int j = 0; j < 4; ++j) {
                int rt = wr * 64 + mi * 16 + lrow * 4 + j;
                if (rt < valid) {
                    float v = acc[mi][ni][j] + bval;
                    if (RELU) v = fmaxf(v, 0.f);
                    int crow = rbase + row0 + rt;
                    if (OUTBF) {
                        outB[((size_t)mod * 1024 + crow) * N + col] = (__bf16)v;
                    } else {
                        int tokid = rows[crow];
                        outF[((size_t)mod * 1024 + tokid) * N + col] = v;
                    }
                }
            }
        }
    }
}

// ---------------------------------------------------------------- poly + sigmoid
__global__ __launch_bounds__(256) void poly_kernel(
    const float* __restrict__ input, const float* __restrict__ moe,
    float* __restrict__ out)
{
    const int b = blockIdx.x, tid = threadIdx.x;
    float4 f0 = *(const float4*)(moe + (size_t)(0 * 1024 + b) * 1024 + tid * 4); // transform
    float4 f1 = *(const float4*)(moe + (size_t)(1 * 1024 + b) * 1024 + tid * 4); // add
    float4 f2 = *(const float4*)(moe + (size_t)(2 * 1024 + b) * 1024 + tid * 4); // quad
    float4 f3 = *(const float4*)(moe + (size_t)(3 * 1024 + b) * 1024 + tid * 4); // cubic
    float4 f4 = *(const float4*)(moe + (size_t)(4 * 1024 + b) * 1024 + tid * 4); // fourth
    const float4* ipv = (const float4*)(input + (size_t)b * 10240);
    float4* opv = (float4*)(out + (size_t)b * 10240);
    #pragma unroll
    for (int t = 0; t < 10; ++t) {
        float4 x = ipv[t * 256 + tid];
        float4 r;
        {
            float i2 = x.x * x.x;
            float p = i2 * (i2 * f4.x + x.x * f3.x + f2.x) + x.x * f0.x + f1.x;
            r.x = 1.f / (1.f + __expf(-p));
        }
        {
            float i2 = x.y * x.y;
            float p = i2 * (i2 * f4.y + x.y * f3.y + f2.y) + x.y * f0.y + f1.y;
            r.y = 1.f / (1.f + __expf(-p));
        }
        {
            float i2 = x.z * x.z;
            float p = i2 * (i2 * f4.z + x.z * f3.z + f2.z) + x.z * f0.z + f1.z;
            r.z = 1.f / (1.f + __expf(-p));
        }
        {
            float i2 = x.w * x.w;
            float p = i2 * (i2 * f4.w + x.w * f3.w + f2.w) + x.w * f0.w + f1.w;
            r.w = 1.f / (1.f + __expf(-p));
        }
        opv[t * 256 + tid] = r;
    }
}

// ---------------------------------------------------------------- loss
__global__ void loss_kernel(const int* __restrict__ counts, float* __restrict__ out_loss)
{
    if (threadIdx.x == 0 && blockIdx.x == 0) {
        float total = 0.f;
        for (int n = 0; n < NMOE; ++n) {
            const float m = 256.f;
            float var = 0.f;
            for (int e = 0; e < 4; ++e) {
                float d = (float)counts[n * 4 + e] - m;
                var += d * d;
            }
            var *= (1.f / 3.f);                       // ddof=1
            float cv2 = var / (m * m + 1e-10f);
            total += 2.f * cv2 * 1e-2f;               // importance == load == counts
        }
        *out_loss = total;
    }
}

// ---------------------------------------------------------------- launch
extern "C" void kernel_launch(void* const* d_in, const int* in_sizes, int n_in,
                              void* d_out, int out_size, void* d_ws, size_t ws_size,
                              hipStream_t stream)
{
    (void)in_sizes; (void)n_in; (void)out_size; (void)ws_size;
    const float* input = (const float*)d_in[0];
    const float* c1w   = (const float*)d_in[1];
    const float* c1b   = (const float*)d_in[2];
    const float* c2w   = (const float*)d_in[3];
    const float* c2b   = (const float*)d_in[4];
    const float* wgate = (const float*)d_in[5];
    const float* w1    = (const float*)d_in[6];
    const float* b1    = (const float*)d_in[7];
    const float* w2    = (const float*)d_in[8];
    const float* b2    = (const float*)d_in[9];
    float* out = (float*)d_out;

    char* ws = (char*)d_ws;
    float*  tok_f32   = (float*)(ws + 0);                 //  4 MB
    __bf16* tok_bf16  = (__bf16*)(ws + 4194304);          //  2 MB
    __bf16* h         = (__bf16*)(ws + 6291456);          // 20.97 MB [5][1024][2048] bf16
    float*  moe_out   = (float*)(ws + 27262976);          // 20.97 MB [5][1024][1024] f32
    int*    rows      = (int*)(ws + 48234496);            // [5][1024]
    int*    expert_id = (int*)(ws + 48254976);            // [5][1024]
    int*    counts    = (int*)(ws + 48275456);            // [5][4]
    int*    row_base  = (int*)(ws + 48275536);            // [5][4]

    hipMemsetAsync(counts, 0, NMOE * NEXP * sizeof(int), stream);

    conv_tok_kernel<<<1024, 256, 0, stream>>>(input, c1w, c1b, c2w, c2b, tok_f32, tok_bf16);
    gating_kernel<<<1280, 256, 0, stream>>>(tok_f32, wgate, expert_id, counts);
    scatter_kernel<<<5, 1024, 0, stream>>>(expert_id, counts, row_base, rows);

    moe_gemm_kernel<1024, 2048, 128, true, true, true><<<dim3(16, 80), 512, 0, stream>>>(
        tok_bf16, w1, b1, rows, counts, row_base, h, nullptr);
    moe_gemm_kernel<2048, 1024, 64, false, false, false><<<dim3(16, 80), 512, 0, stream>>>(
        h, w2, b2, rows, counts, row_base, nullptr, moe_out);

    poly_kernel<<<1024, 256, 0, stream>>>(input, moe_out, out);
    loss_kernel<<<1, 64, 0, stream>>>(counts, out + 10485760);
}